// Round 1
// baseline (3659.708 us; speedup 1.0000x reference)
//
#include <hip/hip_runtime.h>
#include <hip/hip_bf16.h>
#include <cstdint>

typedef __attribute__((ext_vector_type(8))) short s16x8;
typedef __attribute__((ext_vector_type(4))) short s16x4;
typedef __attribute__((ext_vector_type(2))) short s16x2;
typedef __attribute__((ext_vector_type(4))) float f32x4;

#define LTXT 256
#define LIMG 2048
#define LTOT 2304
#define HDIM 3072
#define NHEADS 24
#define HD 128
#define MLPD 12288

__device__ __forceinline__ short f2bf(float f) {
  union { float f; uint32_t u; } v; v.f = f;
  uint32_t r = v.u + 0x7FFFu + ((v.u >> 16) & 1u);
  return (short)(r >> 16);
}
__device__ __forceinline__ float bf2f(short s) {
  union { uint32_t u; float f; } v; v.u = ((uint32_t)(uint16_t)s) << 16;
  return v.f;
}

// ---------------------------------------------------------------------------
// 1) mod GEMV: o = silu(vec) @ mod_w + mod_b  for both streams.
// grid (288, 2), block 256. blockIdx.y: 0=img 1=txt.
// ---------------------------------------------------------------------------
__global__ __launch_bounds__(256)
void mod_gemv(const float* __restrict__ vec,
              const float* __restrict__ w_img, const float* __restrict__ b_img,
              const float* __restrict__ w_txt, const float* __restrict__ b_txt,
              float* __restrict__ mod_img, float* __restrict__ mod_txt)
{
  __shared__ float sv[HDIM];
  const int t = threadIdx.x;
  for (int i = t; i < HDIM; i += 256) {
    float x = vec[i];
    sv[i] = x / (1.f + __expf(-x));
  }
  __syncthreads();
  const float* w = blockIdx.y ? w_txt : w_img;
  const float* bb = blockIdx.y ? b_txt : b_img;
  float* o = blockIdx.y ? mod_txt : mod_img;
  const int col = blockIdx.x * 64 + (t & 63);
  const int kc = t >> 6;
  float acc = 0.f;
  for (int k = kc * 768; k < kc * 768 + 768; ++k)
    acc += sv[k] * w[(size_t)k * 18432 + col];
  __shared__ float part[4][64];
  part[kc][t & 63] = acc;
  __syncthreads();
  if (t < 64) {
    int c = blockIdx.x * 64 + t;
    o[c] = part[0][t] + part[1][t] + part[2][t] + part[3][t] + bb[c];
  }
}

// ---------------------------------------------------------------------------
// 2/8) LayerNorm + modulate: out_bf16 = (1+sc[c])*LN(x)[c] + sh[c]
// grid (2304), block 256 (12 elems/thread). rows < rows_img -> img stream.
// ---------------------------------------------------------------------------
__global__ __launch_bounds__(256)
void ln_mod(const float* __restrict__ xi, const float* __restrict__ xt, int rows_img,
            const float* __restrict__ si, const float* __restrict__ bi,
            const float* __restrict__ st, const float* __restrict__ bt,
            const float* __restrict__ modi, const float* __restrict__ modt,
            int sh_chunk, int sc_chunk,
            short* __restrict__ oi, short* __restrict__ ot)
{
  const int row = blockIdx.x;
  const float *x, *s, *b, *mod;
  short* out;
  if (row < rows_img) {
    x = xi + (size_t)row * HDIM; s = si; b = bi; mod = modi;
    out = oi + (size_t)row * HDIM;
  } else {
    int lr = row - rows_img;
    x = xt + (size_t)lr * HDIM; s = st; b = bt; mod = modt;
    out = ot + (size_t)lr * HDIM;
  }
  const float* sh = mod + (size_t)sh_chunk * HDIM;
  const float* sc = mod + (size_t)sc_chunk * HDIM;
  const int t = threadIdx.x;
  float xv[12];
  {
    float4 a = *(const float4*)(x + t * 12 + 0);
    float4 c = *(const float4*)(x + t * 12 + 4);
    float4 d = *(const float4*)(x + t * 12 + 8);
    xv[0]=a.x; xv[1]=a.y; xv[2]=a.z; xv[3]=a.w;
    xv[4]=c.x; xv[5]=c.y; xv[6]=c.z; xv[7]=c.w;
    xv[8]=d.x; xv[9]=d.y; xv[10]=d.z; xv[11]=d.w;
  }
  float sum = 0.f, ss = 0.f;
  #pragma unroll
  for (int e = 0; e < 12; ++e) { sum += xv[e]; ss += xv[e] * xv[e]; }
  for (int xm = 1; xm < 64; xm <<= 1) {
    sum += __shfl_xor(sum, xm);
    ss  += __shfl_xor(ss, xm);
  }
  __shared__ float red[8];
  const int w = t >> 6, lane = t & 63;
  if (lane == 0) { red[w] = sum; red[4 + w] = ss; }
  __syncthreads();
  sum = red[0] + red[1] + red[2] + red[3];
  ss  = red[4] + red[5] + red[6] + red[7];
  const float mean = sum * (1.f / HDIM);
  const float var = ss * (1.f / HDIM) - mean * mean;
  const float rs = rsqrtf(var + 1e-6f);
  short ov[12];
  #pragma unroll
  for (int e = 0; e < 12; ++e) {
    int c = t * 12 + e;
    float y = (xv[e] - mean) * rs * s[c] + b[c];
    ov[e] = f2bf((1.f + sc[c]) * y + sh[c]);
  }
  #pragma unroll
  for (int j = 0; j < 3; ++j) {
    s16x4 v = { ov[j*4+0], ov[j*4+1], ov[j*4+2], ov[j*4+3] };
    *(s16x4*)(out + t * 12 + j * 4) = v;
  }
}

// ---------------------------------------------------------------------------
// 3/7/9/10) GEMM: C[M,N] = epi(A_bf16[M,K] @ W_f32[K,N] + bias)
// 128x128 tile, BK=64, 4 waves (2x2), each wave 64x64 via 16x16x32 bf16 MFMA.
// W converted fp32->bf16 during staging, stored K-transposed (Ws[col][k]) with
// stride 72 so fragment loads are ds_read_b128.
// EPI: 0 = store bf16; 1 = gelu->bf16; 2 = f32: resid + gate*x; 3 = f32: += gate*x
// ---------------------------------------------------------------------------
template<int EPI>
__global__ __launch_bounds__(256, 2)
void gemm_k(const short* __restrict__ A, const float* __restrict__ W,
            const float* __restrict__ bias, int M, int N, int K,
            void* __restrict__ outp, const float* __restrict__ resid,
            const float* __restrict__ gate)
{
  __shared__ __align__(16) short As[128][72];
  __shared__ __align__(16) short Ws[128][72];
  const int t = threadIdx.x;
  const int lane = t & 63, w = t >> 6;
  const int wr = w >> 1, wc = w & 1;
  const int l15 = lane & 15, lg = lane >> 4;
  const int m0 = blockIdx.x * 128, n0 = blockIdx.y * 128;

  f32x4 acc[4][4];
  #pragma unroll
  for (int i = 0; i < 4; ++i)
    #pragma unroll
    for (int j = 0; j < 4; ++j)
      acc[i][j] = f32x4{0.f, 0.f, 0.f, 0.f};

  for (int kk = 0; kk < K; kk += 64) {
    __syncthreads();
    // stage A (bf16, 128x64): 4 reps of 16B per thread, linear copy
    #pragma unroll
    for (int rep = 0; rep < 4; ++rep) {
      int idx = rep * 256 + t;
      int row = idx >> 3, oct = idx & 7;
      *(s16x8*)(&As[row][oct * 8]) =
          *(const s16x8*)(A + (size_t)(m0 + row) * K + kk + oct * 8);
    }
    // stage W (fp32 -> bf16, transposed into Ws[col][k])
    #pragma unroll
    for (int rep = 0; rep < 4; ++rep) {
      int g2 = w * 4 + rep;                       // 0..15
      int col = (g2 & 3) * 32 + (lane & 31);      // 0..127
      int k0 = ((g2 >> 2) * 16) + ((lane >> 5) * 8); // 0..56
      float f[8];
      #pragma unroll
      for (int i = 0; i < 8; ++i)
        f[i] = W[(size_t)(kk + k0 + i) * N + n0 + col];
      s16x8 p;
      #pragma unroll
      for (int i = 0; i < 8; ++i) p[i] = f2bf(f[i]);
      *(s16x8*)(&Ws[col][k0]) = p;
    }
    __syncthreads();
    #pragma unroll
    for (int ks = 0; ks < 2; ++ks) {
      s16x8 av[4], bv[4];
      #pragma unroll
      for (int mf = 0; mf < 4; ++mf)
        av[mf] = *(const s16x8*)(&As[wr * 64 + mf * 16 + l15][ks * 32 + lg * 8]);
      #pragma unroll
      for (int nf = 0; nf < 4; ++nf)
        bv[nf] = *(const s16x8*)(&Ws[wc * 64 + nf * 16 + l15][ks * 32 + lg * 8]);
      #pragma unroll
      for (int mf = 0; mf < 4; ++mf)
        #pragma unroll
        for (int nf = 0; nf < 4; ++nf)
          acc[mf][nf] = __builtin_amdgcn_mfma_f32_16x16x32_bf16(
              av[mf], bv[nf], acc[mf][nf], 0, 0, 0);
    }
  }
  // epilogue: C layout col=lane&15, row=(lane>>4)*4+reg  [m89]
  #pragma unroll
  for (int mf = 0; mf < 4; ++mf)
    #pragma unroll
    for (int nf = 0; nf < 4; ++nf) {
      int col = n0 + wc * 64 + nf * 16 + l15;
      float bvs = bias[col];
      #pragma unroll
      for (int r = 0; r < 4; ++r) {
        int row = m0 + wr * 64 + mf * 16 + lg * 4 + r;
        float x = acc[mf][nf][r] + bvs;
        if constexpr (EPI == 0) {
          ((short*)outp)[(size_t)row * N + col] = f2bf(x);
        } else if constexpr (EPI == 1) {
          float g = 0.5f * x * (1.f + tanhf(0.7978845608028654f * (x + 0.044715f * x * x * x)));
          ((short*)outp)[(size_t)row * N + col] = f2bf(g);
        } else if constexpr (EPI == 2) {
          ((float*)outp)[(size_t)row * N + col] =
              resid[(size_t)row * N + col] + gate[col] * x;
        } else {
          float* o = (float*)outp;
          size_t ix = (size_t)row * N + col;
          o[ix] = o[ix] + gate[col] * x;
        }
      }
    }
  (void)resid; (void)gate;
}

// ---------------------------------------------------------------------------
// 4) per-(token, head) RMS norm + RoPE for q,k -> [NH][LTOT][HD] bf16
// grid (LTOT/4, NH), block 256 (4 waves, one token each; lane p owns pair 2p,2p+1)
// ---------------------------------------------------------------------------
__global__ __launch_bounds__(256)
void qkvr(const short* __restrict__ qkv, const float* __restrict__ pe,
          const float* __restrict__ qn_img, const float* __restrict__ kn_img,
          const float* __restrict__ qn_txt, const float* __restrict__ kn_txt,
          short* __restrict__ Qh, short* __restrict__ Kh)
{
  const int w = threadIdx.x >> 6, lane = threadIdx.x & 63;
  const int tok = blockIdx.x * 4 + w;
  const int h = blockIdx.y;
  const float* qn = (tok < LTXT) ? qn_txt : qn_img;
  const float* kn = (tok < LTXT) ? kn_txt : kn_img;
  const size_t base = (size_t)tok * 9216 + (size_t)h * HD + lane * 2;
  const float4 p4 = *(const float4*)(pe + ((size_t)tok * 64 + lane) * 4);
  // q
  {
    s16x2 qs = *(const s16x2*)(qkv + base);
    float x0 = bf2f(qs[0]), x1 = bf2f(qs[1]);
    float sq = x0 * x0 + x1 * x1;
    for (int xm = 1; xm < 64; xm <<= 1) sq += __shfl_xor(sq, xm);
    float r = rsqrtf(sq * (1.f / HD) + 1e-6f);
    x0 = x0 * r * qn[lane * 2]; x1 = x1 * r * qn[lane * 2 + 1];
    s16x2 o = { f2bf(p4.x * x0 + p4.y * x1), f2bf(p4.z * x0 + p4.w * x1) };
    *(s16x2*)(Qh + ((size_t)h * LTOT + tok) * HD + lane * 2) = o;
  }
  // k
  {
    s16x2 ks = *(const s16x2*)(qkv + base + HDIM);
    float x0 = bf2f(ks[0]), x1 = bf2f(ks[1]);
    float sq = x0 * x0 + x1 * x1;
    for (int xm = 1; xm < 64; xm <<= 1) sq += __shfl_xor(sq, xm);
    float r = rsqrtf(sq * (1.f / HD) + 1e-6f);
    x0 = x0 * r * kn[lane * 2]; x1 = x1 * r * kn[lane * 2 + 1];
    s16x2 o = { f2bf(p4.x * x0 + p4.y * x1), f2bf(p4.z * x0 + p4.w * x1) };
    *(s16x2*)(Kh + ((size_t)h * LTOT + tok) * HD + lane * 2) = o;
  }
}

// ---------------------------------------------------------------------------
// 5) V transpose: qkv v-slice -> VT[NH][HD][LTOT] bf16. grid (LTOT/64, NH).
// ---------------------------------------------------------------------------
__global__ __launch_bounds__(256)
void vt_k(const short* __restrict__ qkv, short* __restrict__ VT)
{
  __shared__ __align__(16) short Vs[64][136];
  const int h = blockIdx.y, tok0 = blockIdx.x * 64;
  const int t = threadIdx.x;
  #pragma unroll
  for (int rep = 0; rep < 4; ++rep) {
    int idx = rep * 256 + t;
    int tk = idx >> 4, oct = idx & 15;
    *(s16x8*)(&Vs[tk][oct * 8]) =
        *(const s16x8*)(qkv + (size_t)(tok0 + tk) * 9216 + 6144 + (size_t)h * HD + oct * 8);
  }
  __syncthreads();
  #pragma unroll
  for (int rep = 0; rep < 4; ++rep) {
    int idx = rep * 256 + t;
    int d = idx >> 3, tg = idx & 7;
    s16x8 o;
    #pragma unroll
    for (int j = 0; j < 8; ++j) o[j] = Vs[tg * 8 + j][d];
    *(s16x8*)(VT + ((size_t)h * HD + d) * LTOT + tok0 + tg * 8) = o;
  }
}

// ---------------------------------------------------------------------------
// 6) Flash attention. grid (LTOT/128, NH), block 256: wave w owns 32 q-rows.
// K-tiles of 64 keys; online softmax; P transposed through per-wave LDS.
// out: [LTOT][H] bf16, col = h*128+d.
// ---------------------------------------------------------------------------
__global__ __launch_bounds__(256, 2)
void attn_k(const short* __restrict__ Qh, const short* __restrict__ Kh,
            const short* __restrict__ VT, short* __restrict__ out)
{
  __shared__ __align__(16) short Ps[4][32][72];
  const int t = threadIdx.x, lane = t & 63, w = t >> 6;
  const int l15 = lane & 15, lg = lane >> 4;
  const int h = blockIdx.y;
  const int qrow = blockIdx.x * 128 + w * 32;

  s16x8 qf[2][4];
  #pragma unroll
  for (int mf = 0; mf < 2; ++mf)
    #pragma unroll
    for (int ks = 0; ks < 4; ++ks)
      qf[mf][ks] = *(const s16x8*)(Qh + ((size_t)h * LTOT + qrow + mf * 16 + l15) * HD + ks * 32 + lg * 8);

  f32x4 O[2][8];
  #pragma unroll
  for (int mf = 0; mf < 2; ++mf)
    #pragma unroll
    for (int dt = 0; dt < 8; ++dt) O[mf][dt] = f32x4{0.f, 0.f, 0.f, 0.f};
  float mrow[2][4], lrow[2][4];
  #pragma unroll
  for (int mf = 0; mf < 2; ++mf)
    #pragma unroll
    for (int r = 0; r < 4; ++r) { mrow[mf][r] = -1e30f; lrow[mf][r] = 0.f; }

  for (int kt = 0; kt < LTOT / 64; ++kt) {
    const int k0 = kt * 64;
    f32x4 S[2][4];
    #pragma unroll
    for (int mf = 0; mf < 2; ++mf)
      #pragma unroll
      for (int jt = 0; jt < 4; ++jt) S[mf][jt] = f32x4{0.f, 0.f, 0.f, 0.f};
    #pragma unroll
    for (int ks = 0; ks < 4; ++ks)
      #pragma unroll
      for (int jt = 0; jt < 4; ++jt) {
        s16x8 kf = *(const s16x8*)(Kh + ((size_t)h * LTOT + k0 + jt * 16 + l15) * HD + ks * 32 + lg * 8);
        S[0][jt] = __builtin_amdgcn_mfma_f32_16x16x32_bf16(qf[0][ks], kf, S[0][jt], 0, 0, 0);
        S[1][jt] = __builtin_amdgcn_mfma_f32_16x16x32_bf16(qf[1][ks], kf, S[1][jt], 0, 0, 0);
      }
    #pragma unroll
    for (int mf = 0; mf < 2; ++mf) {
      const float scl = 0.08838834764831845f;  // 1/sqrt(128)
      #pragma unroll
      for (int jt = 0; jt < 4; ++jt) S[mf][jt] *= scl;
      float pm[4];
      #pragma unroll
      for (int r = 0; r < 4; ++r)
        pm[r] = fmaxf(fmaxf(S[mf][0][r], S[mf][1][r]), fmaxf(S[mf][2][r], S[mf][3][r]));
      for (int xm = 1; xm < 16; xm <<= 1)
        #pragma unroll
        for (int r = 0; r < 4; ++r) pm[r] = fmaxf(pm[r], __shfl_xor(pm[r], xm));
      f32x4 corrv;
      #pragma unroll
      for (int r = 0; r < 4; ++r) {
        float mn = fmaxf(mrow[mf][r], pm[r]);
        corrv[r] = __expf(mrow[mf][r] - mn);
        mrow[mf][r] = mn;
      }
      float rs[4] = {0.f, 0.f, 0.f, 0.f};
      #pragma unroll
      for (int jt = 0; jt < 4; ++jt)
        #pragma unroll
        for (int r = 0; r < 4; ++r) {
          float p = __expf(S[mf][jt][r] - mrow[mf][r]);
          S[mf][jt][r] = p;
          rs[r] += p;
        }
      for (int xm = 1; xm < 16; xm <<= 1)
        #pragma unroll
        for (int r = 0; r < 4; ++r) rs[r] += __shfl_xor(rs[r], xm);
      #pragma unroll
      for (int r = 0; r < 4; ++r) lrow[mf][r] = lrow[mf][r] * corrv[r] + rs[r];
      #pragma unroll
      for (int dt = 0; dt < 8; ++dt) O[mf][dt] *= corrv;
      #pragma unroll
      for (int jt = 0; jt < 4; ++jt)
        #pragma unroll
        for (int r = 0; r < 4; ++r)
          Ps[w][mf * 16 + lg * 4 + r][jt * 16 + l15] = f2bf(S[mf][jt][r]);
    }
    asm volatile("s_waitcnt lgkmcnt(0)" ::: "memory");
    __builtin_amdgcn_sched_barrier(0);
    #pragma unroll
    for (int kk2 = 0; kk2 < 2; ++kk2) {
      s16x8 pf0 = *(const s16x8*)(&Ps[w][l15][kk2 * 32 + lg * 8]);
      s16x8 pf1 = *(const s16x8*)(&Ps[w][16 + l15][kk2 * 32 + lg * 8]);
      #pragma unroll
      for (int dt = 0; dt < 8; ++dt) {
        s16x8 vf = *(const s16x8*)(VT + ((size_t)h * HD + dt * 16 + l15) * LTOT + k0 + kk2 * 32 + lg * 8);
        O[0][dt] = __builtin_amdgcn_mfma_f32_16x16x32_bf16(pf0, vf, O[0][dt], 0, 0, 0);
        O[1][dt] = __builtin_amdgcn_mfma_f32_16x16x32_bf16(pf1, vf, O[1][dt], 0, 0, 0);
      }
    }
    asm volatile("s_waitcnt lgkmcnt(0)" ::: "memory");
    __builtin_amdgcn_sched_barrier(0);
  }
  #pragma unroll
  for (int mf = 0; mf < 2; ++mf) {
    f32x4 inv;
    #pragma unroll
    for (int r = 0; r < 4; ++r) inv[r] = 1.f / lrow[mf][r];
    #pragma unroll
    for (int dt = 0; dt < 8; ++dt) {
      f32x4 o = O[mf][dt] * inv;
      #pragma unroll
      for (int r = 0; r < 4; ++r)
        out[(size_t)(qrow + mf * 16 + lg * 4 + r) * HDIM + (size_t)h * HD + dt * 16 + l15] = f2bf(o[r]);
    }
  }
}

// ---------------------------------------------------------------------------
extern "C" void kernel_launch(void* const* d_in, const int* in_sizes, int n_in,
                              void* d_out, int out_size, void* d_ws, size_t ws_size,
                              hipStream_t stream)
{
  (void)in_sizes; (void)n_in; (void)out_size; (void)ws_size;
  const float* img = (const float*)d_in[0];
  const float* txt = (const float*)d_in[1];
  const float* vec = (const float*)d_in[2];
  const float* pe  = (const float*)d_in[3];
  const float* Pi[16]; const float* Pt[16];
  for (int i = 0; i < 16; ++i) Pi[i] = (const float*)d_in[4 + i];
  for (int i = 0; i < 16; ++i) Pt[i] = (const float*)d_in[20 + i];
  // per-stream param indices: 0 mod_w,1 mod_b,2 ln1_s,3 ln1_b,4 qkv_w,5 qkv_b,
  // 6 qn,7 kn,8 proj_w,9 proj_b,10 ln2_s,11 ln2_b,12 mlp_w1,13 mlp_b1,14 mlp_w2,15 mlp_b2

  char* ws = (char*)d_ws;
  float* MODI = (float*)(ws + 0);             // 6*3072 f32
  float* MODT = (float*)(ws + 73728);
  short* XMI  = (short*)(ws + 147456);        // 2048*3072 bf16 (also LN2 h)
  short* XMT  = (short*)(ws + 12730368);      // 256*3072 bf16
  short* QKV  = (short*)(ws + 14303232);      // 2304*9216 bf16
  short* QHh  = (short*)(ws + 56770560);      // 24*2304*128 bf16
  short* KHh  = (short*)(ws + 70926336);
  short* VTt  = (short*)(ws + 85082112);      // [24][128][2304]
  short* ATT  = (short*)(ws + 99237888);      // 2304*3072 bf16
  short* H1I  = (short*)(ws + 14303232);      // reuse QKV region (dead by then)
  short* H1T  = (short*)(ws + 64634880);
  float* outI = (float*)d_out;
  float* outT = outI + (size_t)LIMG * HDIM;

  // 1) modulation vectors
  mod_gemv<<<dim3(288, 2), 256, 0, stream>>>(vec, Pi[0], Pi[1], Pt[0], Pt[1], MODI, MODT);
  // 2) LN1 + modulate
  ln_mod<<<dim3(LTOT), 256, 0, stream>>>(img, txt, LIMG, Pi[2], Pi[3], Pt[2], Pt[3],
                                         MODI, MODT, 0, 1, XMI, XMT);
  // 3) QKV GEMMs (txt tokens are rows 0..255 of the concat order)
  gemm_k<0><<<dim3(16, 72), 256, 0, stream>>>(XMI, Pi[4], Pi[5], LIMG, 3 * HDIM, HDIM,
                                              QKV + (size_t)LTXT * 9216, nullptr, nullptr);
  gemm_k<0><<<dim3(2, 72), 256, 0, stream>>>(XMT, Pt[4], Pt[5], LTXT, 3 * HDIM, HDIM,
                                             QKV, nullptr, nullptr);
  // 4) RMS + RoPE -> Q,K heads
  qkvr<<<dim3(LTOT / 4, NHEADS), 256, 0, stream>>>(QKV, pe, Pi[6], Pi[7], Pt[6], Pt[7], QHh, KHh);
  // 5) V transpose
  vt_k<<<dim3(LTOT / 64, NHEADS), 256, 0, stream>>>(QKV, VTt);
  // 6) attention
  attn_k<<<dim3(LTOT / 128, NHEADS), 256, 0, stream>>>(QHh, KHh, VTt, ATT);
  // 7) proj + gated residual -> d_out (f32 residual stream)
  gemm_k<2><<<dim3(16, 24), 256, 0, stream>>>(ATT + (size_t)LTXT * HDIM, Pi[8], Pi[9],
                                              LIMG, HDIM, HDIM, outI, img, MODI + 2 * HDIM);
  gemm_k<2><<<dim3(2, 24), 256, 0, stream>>>(ATT, Pt[8], Pt[9],
                                             LTXT, HDIM, HDIM, outT, txt, MODT + 2 * HDIM);
  // 8) LN2 + modulate
  ln_mod<<<dim3(LTOT), 256, 0, stream>>>(outI, outT, LIMG, Pi[10], Pi[11], Pt[10], Pt[11],
                                         MODI, MODT, 3, 4, XMI, XMT);
  // 9) MLP1 + gelu
  gemm_k<1><<<dim3(16, 96), 256, 0, stream>>>(XMI, Pi[12], Pi[13], LIMG, MLPD, HDIM,
                                              H1I, nullptr, nullptr);
  gemm_k<1><<<dim3(2, 96), 256, 0, stream>>>(XMT, Pt[12], Pt[13], LTXT, MLPD, HDIM,
                                             H1T, nullptr, nullptr);
  // 10) MLP2 + gated residual add into d_out
  gemm_k<3><<<dim3(16, 24), 256, 0, stream>>>(H1I, Pi[14], Pi[15], LIMG, HDIM, MLPD,
                                              outI, nullptr, MODI + 5 * HDIM);
  gemm_k<3><<<dim3(2, 24), 256, 0, stream>>>(H1T, Pt[14], Pt[15], LTXT, HDIM, MLPD,
                                             outT, nullptr, MODT + 5 * HDIM);
}

// Round 2
// 1701.181 us; speedup vs baseline: 2.1513x; 2.1513x over previous
//
#include <hip/hip_runtime.h>
#include <hip/hip_bf16.h>
#include <cstdint>

typedef __attribute__((ext_vector_type(8))) short s16x8;
typedef __attribute__((ext_vector_type(4))) short s16x4;
typedef __attribute__((ext_vector_type(2))) short s16x2;
typedef __attribute__((ext_vector_type(4))) float f32x4;

#define LTXT 256
#define LIMG 2048
#define LTOT 2304
#define HDIM 3072
#define NHEADS 24
#define HD 128
#define MLPD 12288

__device__ __forceinline__ short f2bf(float f) {
  union { float f; uint32_t u; } v; v.f = f;
  uint32_t r = v.u + 0x7FFFu + ((v.u >> 16) & 1u);
  return (short)(r >> 16);
}
__device__ __forceinline__ float bf2f(short s) {
  union { uint32_t u; float f; } v; v.u = ((uint32_t)(uint16_t)s) << 16;
  return v.f;
}

// async global->LDS, 16B per lane, wave-uniform LDS base + lane*16
#define GLDS16(gsrc, ldst)                                                   \
  __builtin_amdgcn_global_load_lds(                                          \
      (const __attribute__((address_space(1))) uint32_t*)(gsrc),             \
      (__attribute__((address_space(3))) uint32_t*)(ldst), 16, 0, 0)

// ---------------------------------------------------------------------------
// 0) weight convert+transpose: Wf fp32 [K][N] -> Wt bf16 [N][K]
// grid (K/64, N/64), block 256. 64x64 tile through LDS.
// ---------------------------------------------------------------------------
__global__ __launch_bounds__(256)
void wconv(const float* __restrict__ Wf, short* __restrict__ Wt, int K, int N)
{
  __shared__ short Ls[64][68];
  const int t = threadIdx.x;
  const int k0 = blockIdx.x * 64, n0 = blockIdx.y * 64;
  #pragma unroll
  for (int rep = 0; rep < 4; ++rep) {
    int idx = rep * 256 + t;
    int k = idx >> 4;
    int n = (idx & 15) * 4;
    float4 v = *(const float4*)(Wf + (size_t)(k0 + k) * N + n0 + n);
    Ls[k][n + 0] = f2bf(v.x); Ls[k][n + 1] = f2bf(v.y);
    Ls[k][n + 2] = f2bf(v.z); Ls[k][n + 3] = f2bf(v.w);
  }
  __syncthreads();
  #pragma unroll
  for (int rep = 0; rep < 4; ++rep) {
    int idx = rep * 256 + t;
    int n = idx >> 4;
    int k = (idx & 15) * 4;
    s16x4 o = { Ls[k + 0][n], Ls[k + 1][n], Ls[k + 2][n], Ls[k + 3][n] };
    *(s16x4*)(Wt + (size_t)(n0 + n) * K + k0 + k) = o;
  }
}

// ---------------------------------------------------------------------------
// 1) mod GEMV: o = silu(vec) @ mod_w + mod_b, float4 per lane.
// grid (72, 2), block 256.
// ---------------------------------------------------------------------------
__global__ __launch_bounds__(256)
void mod_gemv(const float* __restrict__ vec,
              const float* __restrict__ w_img, const float* __restrict__ b_img,
              const float* __restrict__ w_txt, const float* __restrict__ b_txt,
              float* __restrict__ mod_img, float* __restrict__ mod_txt)
{
  __shared__ float sv[HDIM];
  const int t = threadIdx.x;
  for (int i = t; i < HDIM; i += 256) {
    float x = vec[i];
    sv[i] = x / (1.f + __expf(-x));
  }
  __syncthreads();
  const float* w = blockIdx.y ? w_txt : w_img;
  const float* bb = blockIdx.y ? b_txt : b_img;
  float* o = blockIdx.y ? mod_txt : mod_img;
  const int lane = t & 63, kc = t >> 6;
  const int colbase = blockIdx.x * 256 + lane * 4;
  f32x4 acc = {0.f, 0.f, 0.f, 0.f};
  const float* wp = w + (size_t)kc * 768 * 18432 + colbase;
  #pragma unroll 4
  for (int k = 0; k < 768; ++k) {
    float4 wv = *(const float4*)wp;
    float s = sv[kc * 768 + k];
    acc[0] += s * wv.x; acc[1] += s * wv.y;
    acc[2] += s * wv.z; acc[3] += s * wv.w;
    wp += 18432;
  }
  __shared__ f32x4 part[4][64];
  part[kc][lane] = acc;
  __syncthreads();
  if (t < 64) {
    f32x4 r = part[0][t];
    #pragma unroll
    for (int c = 1; c < 4; ++c) r += part[c][t];
    int cb = blockIdx.x * 256 + t * 4;
    float4 bv = *(const float4*)(bb + cb);
    float4 ov; ov.x = r[0] + bv.x; ov.y = r[1] + bv.y;
    ov.z = r[2] + bv.z; ov.w = r[3] + bv.w;
    *(float4*)(o + cb) = ov;
  }
}

// ---------------------------------------------------------------------------
// 2/8) LayerNorm + modulate: out_bf16 = (1+sc[c])*LN(x)[c] + sh[c]
// ---------------------------------------------------------------------------
__global__ __launch_bounds__(256)
void ln_mod(const float* __restrict__ xi, const float* __restrict__ xt, int rows_img,
            const float* __restrict__ si, const float* __restrict__ bi,
            const float* __restrict__ st, const float* __restrict__ bt,
            const float* __restrict__ modi, const float* __restrict__ modt,
            int sh_chunk, int sc_chunk,
            short* __restrict__ oi, short* __restrict__ ot)
{
  const int row = blockIdx.x;
  const float *x, *s, *b, *mod;
  short* out;
  if (row < rows_img) {
    x = xi + (size_t)row * HDIM; s = si; b = bi; mod = modi;
    out = oi + (size_t)row * HDIM;
  } else {
    int lr = row - rows_img;
    x = xt + (size_t)lr * HDIM; s = st; b = bt; mod = modt;
    out = ot + (size_t)lr * HDIM;
  }
  const float* sh = mod + (size_t)sh_chunk * HDIM;
  const float* sc = mod + (size_t)sc_chunk * HDIM;
  const int t = threadIdx.x;
  float xv[12];
  {
    float4 a = *(const float4*)(x + t * 12 + 0);
    float4 c = *(const float4*)(x + t * 12 + 4);
    float4 d = *(const float4*)(x + t * 12 + 8);
    xv[0]=a.x; xv[1]=a.y; xv[2]=a.z; xv[3]=a.w;
    xv[4]=c.x; xv[5]=c.y; xv[6]=c.z; xv[7]=c.w;
    xv[8]=d.x; xv[9]=d.y; xv[10]=d.z; xv[11]=d.w;
  }
  float sum = 0.f, ss = 0.f;
  #pragma unroll
  for (int e = 0; e < 12; ++e) { sum += xv[e]; ss += xv[e] * xv[e]; }
  for (int xm = 1; xm < 64; xm <<= 1) {
    sum += __shfl_xor(sum, xm);
    ss  += __shfl_xor(ss, xm);
  }
  __shared__ float red[8];
  const int w = t >> 6, lane = t & 63;
  if (lane == 0) { red[w] = sum; red[4 + w] = ss; }
  __syncthreads();
  sum = red[0] + red[1] + red[2] + red[3];
  ss  = red[4] + red[5] + red[6] + red[7];
  const float mean = sum * (1.f / HDIM);
  const float var = ss * (1.f / HDIM) - mean * mean;
  const float rs = rsqrtf(var + 1e-6f);
  short ov[12];
  #pragma unroll
  for (int e = 0; e < 12; ++e) {
    int c = t * 12 + e;
    float y = (xv[e] - mean) * rs * s[c] + b[c];
    ov[e] = f2bf((1.f + sc[c]) * y + sh[c]);
  }
  #pragma unroll
  for (int j = 0; j < 3; ++j) {
    s16x4 v = { ov[j*4+0], ov[j*4+1], ov[j*4+2], ov[j*4+3] };
    *(s16x4*)(out + t * 12 + j * 4) = v;
  }
}

// ---------------------------------------------------------------------------
// GEMM (m97 structure): C[M,N] = epi(A_bf16[M,K] @ WT_bf16[N,K]^T + bias)
// 128x128 tile, BK=64, global_load_lds 16B staging, linear LDS, 4 waves 2x2.
// Merged img+txt: tiles with blockIdx.x < split use stream-0 params.
// EPI: 0 = store bf16; 1 = gelu->bf16; 2 = f32: resid + gate*x; 3 = f32: += gate*x
// ---------------------------------------------------------------------------
template<int EPI>
__global__ __launch_bounds__(256)
void gemm_bt(const short* __restrict__ A, int K, int N, int split,
             const short* __restrict__ W0, const short* __restrict__ W1,
             const float* __restrict__ b0, const float* __restrict__ b1,
             void* __restrict__ out0, void* __restrict__ out1,
             const float* __restrict__ r0, const float* __restrict__ r1,
             const float* __restrict__ g0, const float* __restrict__ g1)
{
  __shared__ __align__(16) short As[128 * 64];
  __shared__ __align__(16) short Bs[128 * 64];
  const int t = threadIdx.x;
  const int lane = t & 63, w = t >> 6;
  const int wr = w >> 1, wc = w & 1;
  const int l15 = lane & 15, lg = lane >> 4;
  const int bm = blockIdx.x;
  const bool is1 = bm >= split;
  const int m0 = bm * 128, n0 = blockIdx.y * 128;
  const short* WT = is1 ? W1 : W0;
  const float* bias = is1 ? b1 : b0;

  f32x4 acc[4][4];
  #pragma unroll
  for (int i = 0; i < 4; ++i)
    #pragma unroll
    for (int j = 0; j < 4; ++j)
      acc[i][j] = f32x4{0.f, 0.f, 0.f, 0.f};

  // per-wave staging: wave w stages chunks w*4..w*4+3 of A and of B.
  const int srow = (lane >> 3);        // 0..7
  const int sk = (lane & 7) * 8;       // 0..56
  for (int kk = 0; kk < K; kk += 64) {
    __syncthreads();
    #pragma unroll
    for (int c = 0; c < 4; ++c) {
      int idx = w * 4 + c;             // 0..15
      int row = idx * 8 + srow;        // 0..127
      GLDS16(A + (size_t)(m0 + row) * K + kk + sk, As + idx * 512);
      GLDS16(WT + (size_t)(n0 + row) * K + kk + sk, Bs + idx * 512);
    }
    __syncthreads();
    #pragma unroll
    for (int ks = 0; ks < 2; ++ks) {
      s16x8 av[4], bv[4];
      #pragma unroll
      for (int mf = 0; mf < 4; ++mf)
        av[mf] = *(const s16x8*)(As + (wr * 64 + mf * 16 + l15) * 64 + ks * 32 + lg * 8);
      #pragma unroll
      for (int nf = 0; nf < 4; ++nf)
        bv[nf] = *(const s16x8*)(Bs + (wc * 64 + nf * 16 + l15) * 64 + ks * 32 + lg * 8);
      #pragma unroll
      for (int mf = 0; mf < 4; ++mf)
        #pragma unroll
        for (int nf = 0; nf < 4; ++nf)
          acc[mf][nf] = __builtin_amdgcn_mfma_f32_16x16x32_bf16(
              av[mf], bv[nf], acc[mf][nf], 0, 0, 0);
    }
  }
  // epilogue: C layout col=lane&15, row=(lane>>4)*4+reg
  const int lrbase = m0 - (is1 ? split * 128 : 0);
  #pragma unroll
  for (int mf = 0; mf < 4; ++mf)
    #pragma unroll
    for (int nf = 0; nf < 4; ++nf) {
      int col = n0 + wc * 64 + nf * 16 + l15;
      float bvs = bias[col];
      #pragma unroll
      for (int r = 0; r < 4; ++r) {
        int row = lrbase + wr * 64 + mf * 16 + lg * 4 + r;
        float x = acc[mf][nf][r] + bvs;
        if constexpr (EPI == 0) {
          short* o = (short*)(is1 ? out1 : out0);
          o[(size_t)row * N + col] = f2bf(x);
        } else if constexpr (EPI == 1) {
          float g = 0.5f * x * (1.f + tanhf(0.7978845608028654f * (x + 0.044715f * x * x * x)));
          short* o = (short*)(is1 ? out1 : out0);
          o[(size_t)row * N + col] = f2bf(g);
        } else if constexpr (EPI == 2) {
          const float* resid = is1 ? r1 : r0;
          const float* gate = is1 ? g1 : g0;
          float* o = (float*)(is1 ? out1 : out0);
          o[(size_t)row * N + col] = resid[(size_t)row * N + col] + gate[col] * x;
        } else {
          const float* gate = is1 ? g1 : g0;
          float* o = (float*)(is1 ? out1 : out0);
          size_t ix = (size_t)row * N + col;
          o[ix] = o[ix] + gate[col] * x;
        }
      }
    }
}

// ---------------------------------------------------------------------------
// 4) per-(token, head) RMS norm + RoPE for q,k -> [NH][LTOT][HD] bf16
// ---------------------------------------------------------------------------
__global__ __launch_bounds__(256)
void qkvr(const short* __restrict__ qkv, const float* __restrict__ pe,
          const float* __restrict__ qn_img, const float* __restrict__ kn_img,
          const float* __restrict__ qn_txt, const float* __restrict__ kn_txt,
          short* __restrict__ Qh, short* __restrict__ Kh)
{
  const int w = threadIdx.x >> 6, lane = threadIdx.x & 63;
  const int tok = blockIdx.x * 4 + w;
  const int h = blockIdx.y;
  const float* qn = (tok < LTXT) ? qn_txt : qn_img;
  const float* kn = (tok < LTXT) ? kn_txt : kn_img;
  const size_t base = (size_t)tok * 9216 + (size_t)h * HD + lane * 2;
  const float4 p4 = *(const float4*)(pe + ((size_t)tok * 64 + lane) * 4);
  {
    s16x2 qs = *(const s16x2*)(qkv + base);
    float x0 = bf2f(qs[0]), x1 = bf2f(qs[1]);
    float sq = x0 * x0 + x1 * x1;
    for (int xm = 1; xm < 64; xm <<= 1) sq += __shfl_xor(sq, xm);
    float r = rsqrtf(sq * (1.f / HD) + 1e-6f);
    x0 = x0 * r * qn[lane * 2]; x1 = x1 * r * qn[lane * 2 + 1];
    s16x2 o = { f2bf(p4.x * x0 + p4.y * x1), f2bf(p4.z * x0 + p4.w * x1) };
    *(s16x2*)(Qh + ((size_t)h * LTOT + tok) * HD + lane * 2) = o;
  }
  {
    s16x2 ks = *(const s16x2*)(qkv + base + HDIM);
    float x0 = bf2f(ks[0]), x1 = bf2f(ks[1]);
    float sq = x0 * x0 + x1 * x1;
    for (int xm = 1; xm < 64; xm <<= 1) sq += __shfl_xor(sq, xm);
    float r = rsqrtf(sq * (1.f / HD) + 1e-6f);
    x0 = x0 * r * kn[lane * 2]; x1 = x1 * r * kn[lane * 2 + 1];
    s16x2 o = { f2bf(p4.x * x0 + p4.y * x1), f2bf(p4.z * x0 + p4.w * x1) };
    *(s16x2*)(Kh + ((size_t)h * LTOT + tok) * HD + lane * 2) = o;
  }
}

// ---------------------------------------------------------------------------
// 5) V transpose: qkv v-slice -> VT[NH][HD][LTOT] bf16. grid (LTOT/64, NH).
// ---------------------------------------------------------------------------
__global__ __launch_bounds__(256)
void vt_k(const short* __restrict__ qkv, short* __restrict__ VT)
{
  __shared__ __align__(16) short Vs[64][136];
  const int h = blockIdx.y, tok0 = blockIdx.x * 64;
  const int t = threadIdx.x;
  #pragma unroll
  for (int rep = 0; rep < 4; ++rep) {
    int idx = rep * 256 + t;
    int tk = idx >> 4, oct = idx & 15;
    *(s16x8*)(&Vs[tk][oct * 8]) =
        *(const s16x8*)(qkv + (size_t)(tok0 + tk) * 9216 + 6144 + (size_t)h * HD + oct * 8);
  }
  __syncthreads();
  #pragma unroll
  for (int rep = 0; rep < 4; ++rep) {
    int idx = rep * 256 + t;
    int d = idx >> 3, tg = idx & 7;
    s16x8 o;
    #pragma unroll
    for (int j = 0; j < 8; ++j) o[j] = Vs[tg * 8 + j][d];
    *(s16x8*)(VT + ((size_t)h * HD + d) * LTOT + tok0 + tg * 8) = o;
  }
}

// ---------------------------------------------------------------------------
// 6) Flash attention. grid (LTOT/128, NH), block 256.
// ---------------------------------------------------------------------------
__global__ __launch_bounds__(256, 2)
void attn_k(const short* __restrict__ Qh, const short* __restrict__ Kh,
            const short* __restrict__ VT, short* __restrict__ out)
{
  __shared__ __align__(16) short Ps[4][32][72];
  const int t = threadIdx.x, lane = t & 63, w = t >> 6;
  const int l15 = lane & 15, lg = lane >> 4;
  const int h = blockIdx.y;
  const int qrow = blockIdx.x * 128 + w * 32;

  s16x8 qf[2][4];
  #pragma unroll
  for (int mf = 0; mf < 2; ++mf)
    #pragma unroll
    for (int ks = 0; ks < 4; ++ks)
      qf[mf][ks] = *(const s16x8*)(Qh + ((size_t)h * LTOT + qrow + mf * 16 + l15) * HD + ks * 32 + lg * 8);

  f32x4 O[2][8];
  #pragma unroll
  for (int mf = 0; mf < 2; ++mf)
    #pragma unroll
    for (int dt = 0; dt < 8; ++dt) O[mf][dt] = f32x4{0.f, 0.f, 0.f, 0.f};
  float mrow[2][4], lrow[2][4];
  #pragma unroll
  for (int mf = 0; mf < 2; ++mf)
    #pragma unroll
    for (int r = 0; r < 4; ++r) { mrow[mf][r] = -1e30f; lrow[mf][r] = 0.f; }

  for (int kt = 0; kt < LTOT / 64; ++kt) {
    const int k0 = kt * 64;
    f32x4 S[2][4];
    #pragma unroll
    for (int mf = 0; mf < 2; ++mf)
      #pragma unroll
      for (int jt = 0; jt < 4; ++jt) S[mf][jt] = f32x4{0.f, 0.f, 0.f, 0.f};
    #pragma unroll
    for (int ks = 0; ks < 4; ++ks)
      #pragma unroll
      for (int jt = 0; jt < 4; ++jt) {
        s16x8 kf = *(const s16x8*)(Kh + ((size_t)h * LTOT + k0 + jt * 16 + l15) * HD + ks * 32 + lg * 8);
        S[0][jt] = __builtin_amdgcn_mfma_f32_16x16x32_bf16(qf[0][ks], kf, S[0][jt], 0, 0, 0);
        S[1][jt] = __builtin_amdgcn_mfma_f32_16x16x32_bf16(qf[1][ks], kf, S[1][jt], 0, 0, 0);
      }
    #pragma unroll
    for (int mf = 0; mf < 2; ++mf) {
      const float scl = 0.08838834764831845f;
      #pragma unroll
      for (int jt = 0; jt < 4; ++jt) S[mf][jt] *= scl;
      float pm[4];
      #pragma unroll
      for (int r = 0; r < 4; ++r)
        pm[r] = fmaxf(fmaxf(S[mf][0][r], S[mf][1][r]), fmaxf(S[mf][2][r], S[mf][3][r]));
      for (int xm = 1; xm < 16; xm <<= 1)
        #pragma unroll
        for (int r = 0; r < 4; ++r) pm[r] = fmaxf(pm[r], __shfl_xor(pm[r], xm));
      f32x4 corrv;
      #pragma unroll
      for (int r = 0; r < 4; ++r) {
        float mn = fmaxf(mrow[mf][r], pm[r]);
        corrv[r] = __expf(mrow[mf][r] - mn);
        mrow[mf][r] = mn;
      }
      float rs[4] = {0.f, 0.f, 0.f, 0.f};
      #pragma unroll
      for (int jt = 0; jt < 4; ++jt)
        #pragma unroll
        for (int r = 0; r < 4; ++r) {
          float p = __expf(S[mf][jt][r] - mrow[mf][r]);
          S[mf][jt][r] = p;
          rs[r] += p;
        }
      for (int xm = 1; xm < 16; xm <<= 1)
        #pragma unroll
        for (int r = 0; r < 4; ++r) rs[r] += __shfl_xor(rs[r], xm);
      #pragma unroll
      for (int r = 0; r < 4; ++r) lrow[mf][r] = lrow[mf][r] * corrv[r] + rs[r];
      #pragma unroll
      for (int dt = 0; dt < 8; ++dt) O[mf][dt] *= corrv;
      #pragma unroll
      for (int jt = 0; jt < 4; ++jt)
        #pragma unroll
        for (int r = 0; r < 4; ++r)
          Ps[w][mf * 16 + lg * 4 + r][jt * 16 + l15] = f2bf(S[mf][jt][r]);
    }
    asm volatile("s_waitcnt lgkmcnt(0)" ::: "memory");
    __builtin_amdgcn_sched_barrier(0);
    #pragma unroll
    for (int kk2 = 0; kk2 < 2; ++kk2) {
      s16x8 pf0 = *(const s16x8*)(&Ps[w][l15][kk2 * 32 + lg * 8]);
      s16x8 pf1 = *(const s16x8*)(&Ps[w][16 + l15][kk2 * 32 + lg * 8]);
      #pragma unroll
      for (int dt = 0; dt < 8; ++dt) {
        s16x8 vf = *(const s16x8*)(VT + ((size_t)h * HD + dt * 16 + l15) * LTOT + k0 + kk2 * 32 + lg * 8);
        O[0][dt] = __builtin_amdgcn_mfma_f32_16x16x32_bf16(pf0, vf, O[0][dt], 0, 0, 0);
        O[1][dt] = __builtin_amdgcn_mfma_f32_16x16x32_bf16(pf1, vf, O[1][dt], 0, 0, 0);
      }
    }
    asm volatile("s_waitcnt lgkmcnt(0)" ::: "memory");
    __builtin_amdgcn_sched_barrier(0);
  }
  #pragma unroll
  for (int mf = 0; mf < 2; ++mf) {
    f32x4 inv;
    #pragma unroll
    for (int r = 0; r < 4; ++r) inv[r] = 1.f / lrow[mf][r];
    #pragma unroll
    for (int dt = 0; dt < 8; ++dt) {
      f32x4 o = O[mf][dt] * inv;
      #pragma unroll
      for (int r = 0; r < 4; ++r)
        out[(size_t)(qrow + mf * 16 + lg * 4 + r) * HDIM + (size_t)h * HD + dt * 16 + l15] = f2bf(o[r]);
    }
  }
}

// ---------------------------------------------------------------------------
extern "C" void kernel_launch(void* const* d_in, const int* in_sizes, int n_in,
                              void* d_out, int out_size, void* d_ws, size_t ws_size,
                              hipStream_t stream)
{
  (void)in_sizes; (void)n_in; (void)out_size;
  const float* img = (const float*)d_in[0];
  const float* txt = (const float*)d_in[1];
  const float* vec = (const float*)d_in[2];
  const float* pe  = (const float*)d_in[3];
  const float* Pi[16]; const float* Pt[16];
  for (int i = 0; i < 16; ++i) Pi[i] = (const float*)d_in[4 + i];
  for (int i = 0; i < 16; ++i) Pt[i] = (const float*)d_in[20 + i];
  // 0 mod_w,1 mod_b,2 ln1_s,3 ln1_b,4 qkv_w,5 qkv_b,6 qn,7 kn,8 proj_w,
  // 9 proj_b,10 ln2_s,11 ln2_b,12 mlp_w1,13 mlp_b1,14 mlp_w2,15 mlp_b2

  char* ws = (char*)d_ws;
  float* MODI = (float*)(ws + 0);
  float* MODT = (float*)(ws + 73728);
  short* XMI  = (short*)(ws + 147456);        // [2048][3072] bf16, txt follows
  short* XMT  = (short*)(ws + 12730368);      // [256][3072]  (XM contiguous img-first)
  short* QKV  = (short*)(ws + 14303232);      // [2304][9216] bf16, txt-first rows
  short* QHh  = (short*)(ws + 56770560);      // [24][2304][128]
  short* KHh  = (short*)(ws + 70926336);
  short* VTt  = (short*)(ws + 85082112);      // [24][128][2304]
  short* ATT  = (short*)(ws + 99237888);      // [2304][3072] txt-first rows
  short* H1   = (short*)(ws + 14303232);      // reuse QKV region: [2304][12288] img-first
  short* WTA  = (short*)(ws + 113393664);     // 75.5 MB transposed-weight buf A
  short* WTB  = (short*)(ws + 188891136);     // 75.5 MB transposed-weight buf B
  if (ws_size < (size_t)264388608) return;    // need 264 MB scratch
  float* outI = (float*)d_out;
  float* outT = outI + (size_t)LIMG * HDIM;

  // 1) modulation vectors
  mod_gemv<<<dim3(72, 2), 256, 0, stream>>>(vec, Pi[0], Pi[1], Pt[0], Pt[1], MODI, MODT);
  // 2) LN1 + modulate
  ln_mod<<<dim3(LTOT), 256, 0, stream>>>(img, txt, LIMG, Pi[2], Pi[3], Pt[2], Pt[3],
                                         MODI, MODT, 0, 1, XMI, XMT);
  // 3) QKV: convert weights, merged gemm (XM img-first, split=16)
  wconv<<<dim3(48, 144), 256, 0, stream>>>(Pi[4], WTA, HDIM, 3 * HDIM);
  wconv<<<dim3(48, 144), 256, 0, stream>>>(Pt[4], WTB, HDIM, 3 * HDIM);
  gemm_bt<0><<<dim3(18, 72), 256, 0, stream>>>(XMI, HDIM, 3 * HDIM, 16,
      WTA, WTB, Pi[5], Pt[5],
      QKV + (size_t)LTXT * 9216, QKV, nullptr, nullptr, nullptr, nullptr);
  // 4) RMS + RoPE
  qkvr<<<dim3(LTOT / 4, NHEADS), 256, 0, stream>>>(QKV, pe, Pi[6], Pi[7], Pt[6], Pt[7], QHh, KHh);
  // 5) V transpose
  vt_k<<<dim3(LTOT / 64, NHEADS), 256, 0, stream>>>(QKV, VTt);
  // 6) attention
  attn_k<<<dim3(LTOT / 128, NHEADS), 256, 0, stream>>>(QHh, KHh, VTt, ATT);
  // 7) proj + gated residual -> d_out (ATT txt-first, split=2: stream0=txt)
  wconv<<<dim3(48, 48), 256, 0, stream>>>(Pt[8], WTA, HDIM, HDIM);
  wconv<<<dim3(48, 48), 256, 0, stream>>>(Pi[8], WTB, HDIM, HDIM);
  gemm_bt<2><<<dim3(18, 24), 256, 0, stream>>>(ATT, HDIM, HDIM, 2,
      WTA, WTB, Pt[9], Pi[9], outT, outI, txt, img,
      MODT + 2 * HDIM, MODI + 2 * HDIM);
  // 8) LN2 + modulate
  ln_mod<<<dim3(LTOT), 256, 0, stream>>>(outI, outT, LIMG, Pi[10], Pi[11], Pt[10], Pt[11],
                                         MODI, MODT, 3, 4, XMI, XMT);
  // 9) MLP1 + gelu (XM img-first, split=16) -> H1 img-first
  wconv<<<dim3(48, 192), 256, 0, stream>>>(Pi[12], WTA, HDIM, MLPD);
  wconv<<<dim3(48, 192), 256, 0, stream>>>(Pt[12], WTB, HDIM, MLPD);
  gemm_bt<1><<<dim3(18, 96), 256, 0, stream>>>(XMI, HDIM, MLPD, 16,
      WTA, WTB, Pi[13], Pt[13],
      H1, H1 + (size_t)LIMG * MLPD, nullptr, nullptr, nullptr, nullptr);
  // 10) MLP2 + gated residual add (H1 img-first, split=16)
  wconv<<<dim3(192, 48), 256, 0, stream>>>(Pi[14], WTA, MLPD, HDIM);
  wconv<<<dim3(192, 48), 256, 0, stream>>>(Pt[14], WTB, MLPD, HDIM);
  gemm_bt<3><<<dim3(18, 24), 256, 0, stream>>>(H1, MLPD, HDIM, 16,
      WTA, WTB, Pi[15], Pt[15], outI, outT, nullptr, nullptr,
      MODI + 5 * HDIM, MODT + 5 * HDIM);
}

// Round 3
// 1672.409 us; speedup vs baseline: 2.1883x; 1.0172x over previous
//
#include <hip/hip_runtime.h>
#include <hip/hip_bf16.h>
#include <cstdint>

typedef __attribute__((ext_vector_type(8))) short s16x8;
typedef __attribute__((ext_vector_type(4))) short s16x4;
typedef __attribute__((ext_vector_type(2))) short s16x2;
typedef __attribute__((ext_vector_type(4))) float f32x4;

#define LTXT 256
#define LIMG 2048
#define LTOT 2304
#define HDIM 3072
#define NHEADS 24
#define HD 128
#define MLPD 12288

__device__ __forceinline__ short f2bf(float f) {
  union { float f; uint32_t u; } v; v.f = f;
  uint32_t r = v.u + 0x7FFFu + ((v.u >> 16) & 1u);
  return (short)(r >> 16);
}
__device__ __forceinline__ float bf2f(short s) {
  union { uint32_t u; float f; } v; v.u = ((uint32_t)(uint16_t)s) << 16;
  return v.f;
}

// async global->LDS, 16B per lane, wave-uniform LDS base + lane*16
#define GLDS16(gsrc, ldst)                                                   \
  __builtin_amdgcn_global_load_lds(                                          \
      (const __attribute__((address_space(1))) uint32_t*)(gsrc),             \
      (__attribute__((address_space(3))) uint32_t*)(ldst), 16, 0, 0)

// ---------------------------------------------------------------------------
// 0) weight convert+transpose: Wf fp32 [K][N] -> Wt bf16 [N][K]
// ---------------------------------------------------------------------------
__global__ __launch_bounds__(256)
void wconv(const float* __restrict__ Wf, short* __restrict__ Wt, int K, int N)
{
  __shared__ short Ls[64][68];
  const int t = threadIdx.x;
  const int k0 = blockIdx.x * 64, n0 = blockIdx.y * 64;
  #pragma unroll
  for (int rep = 0; rep < 4; ++rep) {
    int idx = rep * 256 + t;
    int k = idx >> 4;
    int n = (idx & 15) * 4;
    float4 v = *(const float4*)(Wf + (size_t)(k0 + k) * N + n0 + n);
    Ls[k][n + 0] = f2bf(v.x); Ls[k][n + 1] = f2bf(v.y);
    Ls[k][n + 2] = f2bf(v.z); Ls[k][n + 3] = f2bf(v.w);
  }
  __syncthreads();
  #pragma unroll
  for (int rep = 0; rep < 4; ++rep) {
    int idx = rep * 256 + t;
    int n = idx >> 4;
    int k = (idx & 15) * 4;
    s16x4 o = { Ls[k + 0][n], Ls[k + 1][n], Ls[k + 2][n], Ls[k + 3][n] };
    *(s16x4*)(Wt + (size_t)(n0 + n) * K + k0 + k) = o;
  }
}

// ---------------------------------------------------------------------------
// 1) mod GEMV
// ---------------------------------------------------------------------------
__global__ __launch_bounds__(256)
void mod_gemv(const float* __restrict__ vec,
              const float* __restrict__ w_img, const float* __restrict__ b_img,
              const float* __restrict__ w_txt, const float* __restrict__ b_txt,
              float* __restrict__ mod_img, float* __restrict__ mod_txt)
{
  __shared__ float sv[HDIM];
  const int t = threadIdx.x;
  for (int i = t; i < HDIM; i += 256) {
    float x = vec[i];
    sv[i] = x / (1.f + __expf(-x));
  }
  __syncthreads();
  const float* w = blockIdx.y ? w_txt : w_img;
  const float* bb = blockIdx.y ? b_txt : b_img;
  float* o = blockIdx.y ? mod_txt : mod_img;
  const int lane = t & 63, kc = t >> 6;
  const int colbase = blockIdx.x * 256 + lane * 4;
  f32x4 acc = {0.f, 0.f, 0.f, 0.f};
  const float* wp = w + (size_t)kc * 768 * 18432 + colbase;
  #pragma unroll 4
  for (int k = 0; k < 768; ++k) {
    float4 wv = *(const float4*)wp;
    float s = sv[kc * 768 + k];
    acc[0] += s * wv.x; acc[1] += s * wv.y;
    acc[2] += s * wv.z; acc[3] += s * wv.w;
    wp += 18432;
  }
  __shared__ f32x4 part[4][64];
  part[kc][lane] = acc;
  __syncthreads();
  if (t < 64) {
    f32x4 r = part[0][t];
    #pragma unroll
    for (int c = 1; c < 4; ++c) r += part[c][t];
    int cb = blockIdx.x * 256 + t * 4;
    float4 bv = *(const float4*)(bb + cb);
    float4 ov; ov.x = r[0] + bv.x; ov.y = r[1] + bv.y;
    ov.z = r[2] + bv.z; ov.w = r[3] + bv.w;
    *(float4*)(o + cb) = ov;
  }
}

// ---------------------------------------------------------------------------
// 2/8) LayerNorm + modulate
// ---------------------------------------------------------------------------
__global__ __launch_bounds__(256)
void ln_mod(const float* __restrict__ xi, const float* __restrict__ xt, int rows_img,
            const float* __restrict__ si, const float* __restrict__ bi,
            const float* __restrict__ st, const float* __restrict__ bt,
            const float* __restrict__ modi, const float* __restrict__ modt,
            int sh_chunk, int sc_chunk,
            short* __restrict__ oi, short* __restrict__ ot)
{
  const int row = blockIdx.x;
  const float *x, *s, *b, *mod;
  short* out;
  if (row < rows_img) {
    x = xi + (size_t)row * HDIM; s = si; b = bi; mod = modi;
    out = oi + (size_t)row * HDIM;
  } else {
    int lr = row - rows_img;
    x = xt + (size_t)lr * HDIM; s = st; b = bt; mod = modt;
    out = ot + (size_t)lr * HDIM;
  }
  const float* sh = mod + (size_t)sh_chunk * HDIM;
  const float* sc = mod + (size_t)sc_chunk * HDIM;
  const int t = threadIdx.x;
  float xv[12];
  {
    float4 a = *(const float4*)(x + t * 12 + 0);
    float4 c = *(const float4*)(x + t * 12 + 4);
    float4 d = *(const float4*)(x + t * 12 + 8);
    xv[0]=a.x; xv[1]=a.y; xv[2]=a.z; xv[3]=a.w;
    xv[4]=c.x; xv[5]=c.y; xv[6]=c.z; xv[7]=c.w;
    xv[8]=d.x; xv[9]=d.y; xv[10]=d.z; xv[11]=d.w;
  }
  float sum = 0.f, ss = 0.f;
  #pragma unroll
  for (int e = 0; e < 12; ++e) { sum += xv[e]; ss += xv[e] * xv[e]; }
  for (int xm = 1; xm < 64; xm <<= 1) {
    sum += __shfl_xor(sum, xm);
    ss  += __shfl_xor(ss, xm);
  }
  __shared__ float red[8];
  const int w = t >> 6, lane = t & 63;
  if (lane == 0) { red[w] = sum; red[4 + w] = ss; }
  __syncthreads();
  sum = red[0] + red[1] + red[2] + red[3];
  ss  = red[4] + red[5] + red[6] + red[7];
  const float mean = sum * (1.f / HDIM);
  const float var = ss * (1.f / HDIM) - mean * mean;
  const float rs = rsqrtf(var + 1e-6f);
  short ov[12];
  #pragma unroll
  for (int e = 0; e < 12; ++e) {
    int c = t * 12 + e;
    float y = (xv[e] - mean) * rs * s[c] + b[c];
    ov[e] = f2bf((1.f + sc[c]) * y + sh[c]);
  }
  #pragma unroll
  for (int j = 0; j < 3; ++j) {
    s16x4 v = { ov[j*4+0], ov[j*4+1], ov[j*4+2], ov[j*4+3] };
    *(s16x4*)(out + t * 12 + j * 4) = v;
  }
}

// ---------------------------------------------------------------------------
// GEMM 256x256x64, 8 waves (2Mx4N), double-buffered counted-vmcnt pipeline,
// T2 XOR-swizzled LDS (linear dest for global_load_lds, pre-swizzled source),
// T5 setprio around MFMA clusters.
// C[M,N] = epi(A_bf16[M,K] @ WT_bf16[N,K]^T + bias)
// EPI: 0 = store bf16; 1 = gelu->bf16; 2 = f32: resid + gate*x; 3 = f32: += gate*x
// ---------------------------------------------------------------------------
template<int EPI>
__global__ __launch_bounds__(512, 2)
void gemm256(const short* __restrict__ A, int K, int N, int split,
             const short* __restrict__ W0, const short* __restrict__ W1,
             const float* __restrict__ b0, const float* __restrict__ b1,
             void* __restrict__ out0, void* __restrict__ out1,
             const float* __restrict__ r0, const float* __restrict__ r1,
             const float* __restrict__ g0, const float* __restrict__ g1)
{
  // LDS: 2 buffers x (A 256x64 + B 256x64) bf16 = 128 KiB
  __shared__ __align__(16) short lds[2 * 32768];
  const int tid = threadIdx.x;
  const int lane = tid & 63, w = tid >> 6;
  const int wm = w >> 2, wn = w & 3;
  const int l15 = lane & 15, lg = lane >> 4;
  const int x7 = lane & 7;              // == l15 & 7 for fragment rows
  const int bm = blockIdx.x;
  const bool is1 = bm >= split;
  const int m0 = bm * 256, n0 = blockIdx.y * 256;
  const short* WT = is1 ? W1 : W0;
  const float* bias = is1 ? b1 : b0;
  const int nt = K >> 6;

  // staging constants: thread stages chunk idx = cc*512 + w*64 + lane,
  // row = cc*64 + w*8 + (lane>>3), physical chunk pc = lane&7,
  // logical chunk fetched = pc ^ (row&7) = (lane&7) ^ (lane>>3)
  const int srow = w * 8 + (lane >> 3);
  const int lcw = (lane & 7) ^ (lane >> 3);

  f32x4 acc[8][4];
  #pragma unroll
  for (int i = 0; i < 8; ++i)
    #pragma unroll
    for (int j = 0; j < 4; ++j)
      acc[i][j] = f32x4{0.f, 0.f, 0.f, 0.f};

  auto stage = [&](int tt, int cb) {
    short* LA = &lds[cb * 32768];
    short* LB = LA + 16384;
    const size_t kk = (size_t)tt * 64;
    #pragma unroll
    for (int cc = 0; cc < 4; ++cc) {
      const int rr = cc * 64 + srow;
      GLDS16(A + (size_t)(m0 + rr) * K + kk + lcw * 8, LA + (cc * 512 + w * 64) * 8);
      GLDS16(WT + (size_t)(n0 + rr) * K + kk + lcw * 8, LB + (cc * 512 + w * 64) * 8);
    }
  };

  // prologue: stage tiles 0 and 1
  stage(0, 0);
  stage(1, 1);

  const int rA0 = wm * 128 + l15;       // A fragment base row
  const int rB0 = wn * 64 + l15;        // B fragment base row

  for (int t = 0; t < nt; ++t) {
    const int c = t & 1;
    if (t == nt - 1) { asm volatile("s_waitcnt vmcnt(0)" ::: "memory"); }
    else             { asm volatile("s_waitcnt vmcnt(8)" ::: "memory"); }
    __builtin_amdgcn_s_barrier();
    __builtin_amdgcn_sched_barrier(0);
    const short* As = &lds[c * 32768];
    const short* Bs = As + 16384;
    #pragma unroll
    for (int ks = 0; ks < 2; ++ks) {
      const int cofs = ((ks * 4 + lg) ^ x7) * 8;
      s16x8 av[8], bv[4];
      #pragma unroll
      for (int mf = 0; mf < 8; ++mf)
        av[mf] = *(const s16x8*)(As + (rA0 + mf * 16) * 64 + cofs);
      #pragma unroll
      for (int nf = 0; nf < 4; ++nf)
        bv[nf] = *(const s16x8*)(Bs + (rB0 + nf * 16) * 64 + cofs);
      __builtin_amdgcn_s_setprio(1);
      #pragma unroll
      for (int mf = 0; mf < 8; ++mf)
        #pragma unroll
        for (int nf = 0; nf < 4; ++nf)
          acc[mf][nf] = __builtin_amdgcn_mfma_f32_16x16x32_bf16(
              av[mf], bv[nf], acc[mf][nf], 0, 0, 0);
      __builtin_amdgcn_s_setprio(0);
    }
    asm volatile("s_waitcnt lgkmcnt(0)" ::: "memory");
    __builtin_amdgcn_s_barrier();
    __builtin_amdgcn_sched_barrier(0);
    if (t + 2 < nt) stage(t + 2, c);
  }

  // epilogue: C frag layout col=lane&15, row=(lane>>4)*4+reg
  const int lrbase = m0 - (is1 ? split * 256 : 0);
  #pragma unroll
  for (int mf = 0; mf < 8; ++mf)
    #pragma unroll
    for (int nf = 0; nf < 4; ++nf) {
      int col = n0 + wn * 64 + nf * 16 + l15;
      float bvs = bias[col];
      #pragma unroll
      for (int r = 0; r < 4; ++r) {
        int row = lrbase + wm * 128 + mf * 16 + lg * 4 + r;
        float x = acc[mf][nf][r] + bvs;
        if constexpr (EPI == 0) {
          short* o = (short*)(is1 ? out1 : out0);
          o[(size_t)row * N + col] = f2bf(x);
        } else if constexpr (EPI == 1) {
          float g = 0.5f * x * (1.f + tanhf(0.7978845608028654f * (x + 0.044715f * x * x * x)));
          short* o = (short*)(is1 ? out1 : out0);
          o[(size_t)row * N + col] = f2bf(g);
        } else if constexpr (EPI == 2) {
          const float* resid = is1 ? r1 : r0;
          const float* gate = is1 ? g1 : g0;
          float* o = (float*)(is1 ? out1 : out0);
          o[(size_t)row * N + col] = resid[(size_t)row * N + col] + gate[col] * x;
        } else {
          const float* gate = is1 ? g1 : g0;
          float* o = (float*)(is1 ? out1 : out0);
          size_t ix = (size_t)row * N + col;
          o[ix] = o[ix] + gate[col] * x;
        }
      }
    }
}

// ---------------------------------------------------------------------------
// 4) per-(token, head) RMS norm + RoPE for q,k -> [NH][LTOT][HD] bf16
// ---------------------------------------------------------------------------
__global__ __launch_bounds__(256)
void qkvr(const short* __restrict__ qkv, const float* __restrict__ pe,
          const float* __restrict__ qn_img, const float* __restrict__ kn_img,
          const float* __restrict__ qn_txt, const float* __restrict__ kn_txt,
          short* __restrict__ Qh, short* __restrict__ Kh)
{
  const int w = threadIdx.x >> 6, lane = threadIdx.x & 63;
  const int tok = blockIdx.x * 4 + w;
  const int h = blockIdx.y;
  const float* qn = (tok < LTXT) ? qn_txt : qn_img;
  const float* kn = (tok < LTXT) ? kn_txt : kn_img;
  const size_t base = (size_t)tok * 9216 + (size_t)h * HD + lane * 2;
  const float4 p4 = *(const float4*)(pe + ((size_t)tok * 64 + lane) * 4);
  {
    s16x2 qs = *(const s16x2*)(qkv + base);
    float x0 = bf2f(qs[0]), x1 = bf2f(qs[1]);
    float sq = x0 * x0 + x1 * x1;
    for (int xm = 1; xm < 64; xm <<= 1) sq += __shfl_xor(sq, xm);
    float r = rsqrtf(sq * (1.f / HD) + 1e-6f);
    x0 = x0 * r * qn[lane * 2]; x1 = x1 * r * qn[lane * 2 + 1];
    s16x2 o = { f2bf(p4.x * x0 + p4.y * x1), f2bf(p4.z * x0 + p4.w * x1) };
    *(s16x2*)(Qh + ((size_t)h * LTOT + tok) * HD + lane * 2) = o;
  }
  {
    s16x2 ks = *(const s16x2*)(qkv + base + HDIM);
    float x0 = bf2f(ks[0]), x1 = bf2f(ks[1]);
    float sq = x0 * x0 + x1 * x1;
    for (int xm = 1; xm < 64; xm <<= 1) sq += __shfl_xor(sq, xm);
    float r = rsqrtf(sq * (1.f / HD) + 1e-6f);
    x0 = x0 * r * kn[lane * 2]; x1 = x1 * r * kn[lane * 2 + 1];
    s16x2 o = { f2bf(p4.x * x0 + p4.y * x1), f2bf(p4.z * x0 + p4.w * x1) };
    *(s16x2*)(Kh + ((size_t)h * LTOT + tok) * HD + lane * 2) = o;
  }
}

// ---------------------------------------------------------------------------
// 5) V transpose: qkv v-slice -> VT[NH][HD][LTOT] bf16. grid (LTOT/64, NH).
// ---------------------------------------------------------------------------
__global__ __launch_bounds__(256)
void vt_k(const short* __restrict__ qkv, short* __restrict__ VT)
{
  __shared__ __align__(16) short Vs[64][136];
  const int h = blockIdx.y, tok0 = blockIdx.x * 64;
  const int t = threadIdx.x;
  #pragma unroll
  for (int rep = 0; rep < 4; ++rep) {
    int idx = rep * 256 + t;
    int tk = idx >> 4, oct = idx & 15;
    *(s16x8*)(&Vs[tk][oct * 8]) =
        *(const s16x8*)(qkv + (size_t)(tok0 + tk) * 9216 + 6144 + (size_t)h * HD + oct * 8);
  }
  __syncthreads();
  #pragma unroll
  for (int rep = 0; rep < 4; ++rep) {
    int idx = rep * 256 + t;
    int d = idx >> 3, tg = idx & 7;
    s16x8 o;
    #pragma unroll
    for (int j = 0; j < 8; ++j) o[j] = Vs[tg * 8 + j][d];
    *(s16x8*)(VT + ((size_t)h * HD + d) * LTOT + tok0 + tg * 8) = o;
  }
}

// ---------------------------------------------------------------------------
// 6) Flash attention. grid (LTOT/128, NH), block 256.
// ---------------------------------------------------------------------------
__global__ __launch_bounds__(256, 2)
void attn_k(const short* __restrict__ Qh, const short* __restrict__ Kh,
            const short* __restrict__ VT, short* __restrict__ out)
{
  __shared__ __align__(16) short Ps[4][32][72];
  const int t = threadIdx.x, lane = t & 63, w = t >> 6;
  const int l15 = lane & 15, lg = lane >> 4;
  const int h = blockIdx.y;
  const int qrow = blockIdx.x * 128 + w * 32;

  s16x8 qf[2][4];
  #pragma unroll
  for (int mf = 0; mf < 2; ++mf)
    #pragma unroll
    for (int ks = 0; ks < 4; ++ks)
      qf[mf][ks] = *(const s16x8*)(Qh + ((size_t)h * LTOT + qrow + mf * 16 + l15) * HD + ks * 32 + lg * 8);

  f32x4 O[2][8];
  #pragma unroll
  for (int mf = 0; mf < 2; ++mf)
    #pragma unroll
    for (int dt = 0; dt < 8; ++dt) O[mf][dt] = f32x4{0.f, 0.f, 0.f, 0.f};
  float mrow[2][4], lrow[2][4];
  #pragma unroll
  for (int mf = 0; mf < 2; ++mf)
    #pragma unroll
    for (int r = 0; r < 4; ++r) { mrow[mf][r] = -1e30f; lrow[mf][r] = 0.f; }

  for (int kt = 0; kt < LTOT / 64; ++kt) {
    const int k0 = kt * 64;
    f32x4 S[2][4];
    #pragma unroll
    for (int mf = 0; mf < 2; ++mf)
      #pragma unroll
      for (int jt = 0; jt < 4; ++jt) S[mf][jt] = f32x4{0.f, 0.f, 0.f, 0.f};
    #pragma unroll
    for (int ks = 0; ks < 4; ++ks)
      #pragma unroll
      for (int jt = 0; jt < 4; ++jt) {
        s16x8 kf = *(const s16x8*)(Kh + ((size_t)h * LTOT + k0 + jt * 16 + l15) * HD + ks * 32 + lg * 8);
        S[0][jt] = __builtin_amdgcn_mfma_f32_16x16x32_bf16(qf[0][ks], kf, S[0][jt], 0, 0, 0);
        S[1][jt] = __builtin_amdgcn_mfma_f32_16x16x32_bf16(qf[1][ks], kf, S[1][jt], 0, 0, 0);
      }
    #pragma unroll
    for (int mf = 0; mf < 2; ++mf) {
      const float scl = 0.08838834764831845f;
      #pragma unroll
      for (int jt = 0; jt < 4; ++jt) S[mf][jt] *= scl;
      float pm[4];
      #pragma unroll
      for (int r = 0; r < 4; ++r)
        pm[r] = fmaxf(fmaxf(S[mf][0][r], S[mf][1][r]), fmaxf(S[mf][2][r], S[mf][3][r]));
      for (int xm = 1; xm < 16; xm <<= 1)
        #pragma unroll
        for (int r = 0; r < 4; ++r) pm[r] = fmaxf(pm[r], __shfl_xor(pm[r], xm));
      f32x4 corrv;
      #pragma unroll
      for (int r = 0; r < 4; ++r) {
        float mn = fmaxf(mrow[mf][r], pm[r]);
        corrv[r] = __expf(mrow[mf][r] - mn);
        mrow[mf][r] = mn;
      }
      float rs[4] = {0.f, 0.f, 0.f, 0.f};
      #pragma unroll
      for (int jt = 0; jt < 4; ++jt)
        #pragma unroll
        for (int r = 0; r < 4; ++r) {
          float p = __expf(S[mf][jt][r] - mrow[mf][r]);
          S[mf][jt][r] = p;
          rs[r] += p;
        }
      for (int xm = 1; xm < 16; xm <<= 1)
        #pragma unroll
        for (int r = 0; r < 4; ++r) rs[r] += __shfl_xor(rs[r], xm);
      #pragma unroll
      for (int r = 0; r < 4; ++r) lrow[mf][r] = lrow[mf][r] * corrv[r] + rs[r];
      #pragma unroll
      for (int dt = 0; dt < 8; ++dt) O[mf][dt] *= corrv;
      #pragma unroll
      for (int jt = 0; jt < 4; ++jt)
        #pragma unroll
        for (int r = 0; r < 4; ++r)
          Ps[w][mf * 16 + lg * 4 + r][jt * 16 + l15] = f2bf(S[mf][jt][r]);
    }
    asm volatile("s_waitcnt lgkmcnt(0)" ::: "memory");
    __builtin_amdgcn_sched_barrier(0);
    #pragma unroll
    for (int kk2 = 0; kk2 < 2; ++kk2) {
      s16x8 pf0 = *(const s16x8*)(&Ps[w][l15][kk2 * 32 + lg * 8]);
      s16x8 pf1 = *(const s16x8*)(&Ps[w][16 + l15][kk2 * 32 + lg * 8]);
      #pragma unroll
      for (int dt = 0; dt < 8; ++dt) {
        s16x8 vf = *(const s16x8*)(VT + ((size_t)h * HD + dt * 16 + l15) * LTOT + k0 + kk2 * 32 + lg * 8);
        O[0][dt] = __builtin_amdgcn_mfma_f32_16x16x32_bf16(pf0, vf, O[0][dt], 0, 0, 0);
        O[1][dt] = __builtin_amdgcn_mfma_f32_16x16x32_bf16(pf1, vf, O[1][dt], 0, 0, 0);
      }
    }
    asm volatile("s_waitcnt lgkmcnt(0)" ::: "memory");
    __builtin_amdgcn_sched_barrier(0);
  }
  #pragma unroll
  for (int mf = 0; mf < 2; ++mf) {
    f32x4 inv;
    #pragma unroll
    for (int r = 0; r < 4; ++r) inv[r] = 1.f / lrow[mf][r];
    #pragma unroll
    for (int dt = 0; dt < 8; ++dt) {
      f32x4 o = O[mf][dt] * inv;
      #pragma unroll
      for (int r = 0; r < 4; ++r)
        out[(size_t)(qrow + mf * 16 + lg * 4 + r) * HDIM + (size_t)h * HD + dt * 16 + l15] = f2bf(o[r]);
    }
  }
}

// ---------------------------------------------------------------------------
extern "C" void kernel_launch(void* const* d_in, const int* in_sizes, int n_in,
                              void* d_out, int out_size, void* d_ws, size_t ws_size,
                              hipStream_t stream)
{
  (void)in_sizes; (void)n_in; (void)out_size;
  const float* img = (const float*)d_in[0];
  const float* txt = (const float*)d_in[1];
  const float* vec = (const float*)d_in[2];
  const float* pe  = (const float*)d_in[3];
  const float* Pi[16]; const float* Pt[16];
  for (int i = 0; i < 16; ++i) Pi[i] = (const float*)d_in[4 + i];
  for (int i = 0; i < 16; ++i) Pt[i] = (const float*)d_in[20 + i];
  // 0 mod_w,1 mod_b,2 ln1_s,3 ln1_b,4 qkv_w,5 qkv_b,6 qn,7 kn,8 proj_w,
  // 9 proj_b,10 ln2_s,11 ln2_b,12 mlp_w1,13 mlp_b1,14 mlp_w2,15 mlp_b2

  char* ws = (char*)d_ws;
  float* MODI = (float*)(ws + 0);
  float* MODT = (float*)(ws + 73728);
  short* XMI  = (short*)(ws + 147456);        // [2304][3072] bf16 img-first
  short* XMT  = (short*)(ws + 12730368);
  short* QKV  = (short*)(ws + 14303232);      // [2304][9216] bf16, txt-first rows
  short* QHh  = (short*)(ws + 56770560);      // [24][2304][128]
  short* KHh  = (short*)(ws + 70926336);
  short* VTt  = (short*)(ws + 85082112);      // [24][128][2304]
  short* ATT  = (short*)(ws + 99237888);      // [2304][3072] txt-first rows
  short* H1   = (short*)(ws + 14303232);      // reuse QKV+QH region: [2304][12288] img-first
  short* WTA  = (short*)(ws + 113393664);     // 75.5 MB transposed-weight buf A
  short* WTB  = (short*)(ws + 188891136);     // 75.5 MB transposed-weight buf B
  if (ws_size < (size_t)264388608) return;
  float* outI = (float*)d_out;
  float* outT = outI + (size_t)LIMG * HDIM;

  // 1) modulation vectors
  mod_gemv<<<dim3(72, 2), 256, 0, stream>>>(vec, Pi[0], Pi[1], Pt[0], Pt[1], MODI, MODT);
  // 2) LN1 + modulate
  ln_mod<<<dim3(LTOT), 256, 0, stream>>>(img, txt, LIMG, Pi[2], Pi[3], Pt[2], Pt[3],
                                         MODI, MODT, 0, 1, XMI, XMT);
  // 3) QKV: convert weights, merged gemm (XM img-first, split=8)
  wconv<<<dim3(48, 144), 256, 0, stream>>>(Pi[4], WTA, HDIM, 3 * HDIM);
  wconv<<<dim3(48, 144), 256, 0, stream>>>(Pt[4], WTB, HDIM, 3 * HDIM);
  gemm256<0><<<dim3(9, 36), 512, 0, stream>>>(XMI, HDIM, 3 * HDIM, 8,
      WTA, WTB, Pi[5], Pt[5],
      QKV + (size_t)LTXT * 9216, QKV, nullptr, nullptr, nullptr, nullptr);
  // 4) RMS + RoPE
  qkvr<<<dim3(LTOT / 4, NHEADS), 256, 0, stream>>>(QKV, pe, Pi[6], Pi[7], Pt[6], Pt[7], QHh, KHh);
  // 5) V transpose
  vt_k<<<dim3(LTOT / 64, NHEADS), 256, 0, stream>>>(QKV, VTt);
  // 6) attention
  attn_k<<<dim3(LTOT / 128, NHEADS), 256, 0, stream>>>(QHh, KHh, VTt, ATT);
  // 7) proj + gated residual -> d_out (ATT txt-first, split=1: stream0=txt)
  wconv<<<dim3(48, 48), 256, 0, stream>>>(Pt[8], WTA, HDIM, HDIM);
  wconv<<<dim3(48, 48), 256, 0, stream>>>(Pi[8], WTB, HDIM, HDIM);
  gemm256<2><<<dim3(9, 12), 512, 0, stream>>>(ATT, HDIM, HDIM, 1,
      WTA, WTB, Pt[9], Pi[9], outT, outI, txt, img,
      MODT + 2 * HDIM, MODI + 2 * HDIM);
  // 8) LN2 + modulate
  ln_mod<<<dim3(LTOT), 256, 0, stream>>>(outI, outT, LIMG, Pi[10], Pi[11], Pt[10], Pt[11],
                                         MODI, MODT, 3, 4, XMI, XMT);
  // 9) MLP1 + gelu (XM img-first, split=8) -> H1 img-first
  wconv<<<dim3(48, 192), 256, 0, stream>>>(Pi[12], WTA, HDIM, MLPD);
  wconv<<<dim3(48, 192), 256, 0, stream>>>(Pt[12], WTB, HDIM, MLPD);
  gemm256<1><<<dim3(9, 48), 512, 0, stream>>>(XMI, HDIM, MLPD, 8,
      WTA, WTB, Pi[13], Pt[13],
      H1, H1 + (size_t)LIMG * MLPD, nullptr, nullptr, nullptr, nullptr);
  // 10) MLP2 + gated residual add (H1 img-first, split=8)
  wconv<<<dim3(192, 48), 256, 0, stream>>>(Pi[14], WTA, MLPD, HDIM);
  wconv<<<dim3(192, 48), 256, 0, stream>>>(Pt[14], WTB, MLPD, HDIM);
  gemm256<3><<<dim3(9, 12), 512, 0, stream>>>(H1, MLPD, HDIM, 8,
      WTA, WTB, Pi[15], Pt[15], outI, outT, nullptr, nullptr,
      MODI + 5 * HDIM, MODT + 5 * HDIM);
}

// Round 4
// 1544.759 us; speedup vs baseline: 2.3691x; 1.0826x over previous
//
#include <hip/hip_runtime.h>
#include <hip/hip_bf16.h>
#include <cstdint>

typedef __attribute__((ext_vector_type(8))) short s16x8;
typedef __attribute__((ext_vector_type(4))) short s16x4;
typedef __attribute__((ext_vector_type(2))) short s16x2;
typedef __attribute__((ext_vector_type(4))) float f32x4;

#define LTXT 256
#define LIMG 2048
#define LTOT 2304
#define HDIM 3072
#define NHEADS 24
#define HD 128
#define MLPD 12288

__device__ __forceinline__ short f2bf(float f) {
  union { float f; uint32_t u; } v; v.f = f;
  uint32_t r = v.u + 0x7FFFu + ((v.u >> 16) & 1u);
  return (short)(r >> 16);
}
__device__ __forceinline__ float bf2f(short s) {
  union { uint32_t u; float f; } v; v.u = ((uint32_t)(uint16_t)s) << 16;
  return v.f;
}

// async global->LDS, 16B per lane, wave-uniform LDS base + lane*16
#define GLDS16(gsrc, ldst)                                                   \
  __builtin_amdgcn_global_load_lds(                                          \
      (const __attribute__((address_space(1))) uint32_t*)(gsrc),             \
      (__attribute__((address_space(3))) uint32_t*)(ldst), 16, 0, 0)

// ---------------------------------------------------------------------------
// 0) weight convert+transpose: Wf fp32 [K][N] -> Wt bf16 [N][K]
// ---------------------------------------------------------------------------
__global__ __launch_bounds__(256)
void wconv(const float* __restrict__ Wf, short* __restrict__ Wt, int K, int N)
{
  __shared__ short Ls[64][68];
  const int t = threadIdx.x;
  const int k0 = blockIdx.x * 64, n0 = blockIdx.y * 64;
  #pragma unroll
  for (int rep = 0; rep < 4; ++rep) {
    int idx = rep * 256 + t;
    int k = idx >> 4;
    int n = (idx & 15) * 4;
    float4 v = *(const float4*)(Wf + (size_t)(k0 + k) * N + n0 + n);
    Ls[k][n + 0] = f2bf(v.x); Ls[k][n + 1] = f2bf(v.y);
    Ls[k][n + 2] = f2bf(v.z); Ls[k][n + 3] = f2bf(v.w);
  }
  __syncthreads();
  #pragma unroll
  for (int rep = 0; rep < 4; ++rep) {
    int idx = rep * 256 + t;
    int n = idx >> 4;
    int k = (idx & 15) * 4;
    s16x4 o = { Ls[k + 0][n], Ls[k + 1][n], Ls[k + 2][n], Ls[k + 3][n] };
    *(s16x4*)(Wt + (size_t)(n0 + n) * K + k0 + k) = o;
  }
}

// ---------------------------------------------------------------------------
// 1) mod GEMV
// ---------------------------------------------------------------------------
__global__ __launch_bounds__(256)
void mod_gemv(const float* __restrict__ vec,
              const float* __restrict__ w_img, const float* __restrict__ b_img,
              const float* __restrict__ w_txt, const float* __restrict__ b_txt,
              float* __restrict__ mod_img, float* __restrict__ mod_txt)
{
  __shared__ float sv[HDIM];
  const int t = threadIdx.x;
  for (int i = t; i < HDIM; i += 256) {
    float x = vec[i];
    sv[i] = x / (1.f + __expf(-x));
  }
  __syncthreads();
  const float* w = blockIdx.y ? w_txt : w_img;
  const float* bb = blockIdx.y ? b_txt : b_img;
  float* o = blockIdx.y ? mod_txt : mod_img;
  const int lane = t & 63, kc = t >> 6;
  const int colbase = blockIdx.x * 256 + lane * 4;
  f32x4 acc = {0.f, 0.f, 0.f, 0.f};
  const float* wp = w + (size_t)kc * 768 * 18432 + colbase;
  #pragma unroll 4
  for (int k = 0; k < 768; ++k) {
    float4 wv = *(const float4*)wp;
    float s = sv[kc * 768 + k];
    acc[0] += s * wv.x; acc[1] += s * wv.y;
    acc[2] += s * wv.z; acc[3] += s * wv.w;
    wp += 18432;
  }
  __shared__ f32x4 part[4][64];
  part[kc][lane] = acc;
  __syncthreads();
  if (t < 64) {
    f32x4 r = part[0][t];
    #pragma unroll
    for (int c = 1; c < 4; ++c) r += part[c][t];
    int cb = blockIdx.x * 256 + t * 4;
    float4 bv = *(const float4*)(bb + cb);
    float4 ov; ov.x = r[0] + bv.x; ov.y = r[1] + bv.y;
    ov.z = r[2] + bv.z; ov.w = r[3] + bv.w;
    *(float4*)(o + cb) = ov;
  }
}

// ---------------------------------------------------------------------------
// 2/8) LayerNorm + modulate
// ---------------------------------------------------------------------------
__global__ __launch_bounds__(256)
void ln_mod(const float* __restrict__ xi, const float* __restrict__ xt, int rows_img,
            const float* __restrict__ si, const float* __restrict__ bi,
            const float* __restrict__ st, const float* __restrict__ bt,
            const float* __restrict__ modi, const float* __restrict__ modt,
            int sh_chunk, int sc_chunk,
            short* __restrict__ oi, short* __restrict__ ot)
{
  const int row = blockIdx.x;
  const float *x, *s, *b, *mod;
  short* out;
  if (row < rows_img) {
    x = xi + (size_t)row * HDIM; s = si; b = bi; mod = modi;
    out = oi + (size_t)row * HDIM;
  } else {
    int lr = row - rows_img;
    x = xt + (size_t)lr * HDIM; s = st; b = bt; mod = modt;
    out = ot + (size_t)lr * HDIM;
  }
  const float* sh = mod + (size_t)sh_chunk * HDIM;
  const float* sc = mod + (size_t)sc_chunk * HDIM;
  const int t = threadIdx.x;
  float xv[12];
  {
    float4 a = *(const float4*)(x + t * 12 + 0);
    float4 c = *(const float4*)(x + t * 12 + 4);
    float4 d = *(const float4*)(x + t * 12 + 8);
    xv[0]=a.x; xv[1]=a.y; xv[2]=a.z; xv[3]=a.w;
    xv[4]=c.x; xv[5]=c.y; xv[6]=c.z; xv[7]=c.w;
    xv[8]=d.x; xv[9]=d.y; xv[10]=d.z; xv[11]=d.w;
  }
  float sum = 0.f, ss = 0.f;
  #pragma unroll
  for (int e = 0; e < 12; ++e) { sum += xv[e]; ss += xv[e] * xv[e]; }
  for (int xm = 1; xm < 64; xm <<= 1) {
    sum += __shfl_xor(sum, xm);
    ss  += __shfl_xor(ss, xm);
  }
  __shared__ float red[8];
  const int w = t >> 6, lane = t & 63;
  if (lane == 0) { red[w] = sum; red[4 + w] = ss; }
  __syncthreads();
  sum = red[0] + red[1] + red[2] + red[3];
  ss  = red[4] + red[5] + red[6] + red[7];
  const float mean = sum * (1.f / HDIM);
  const float var = ss * (1.f / HDIM) - mean * mean;
  const float rs = rsqrtf(var + 1e-6f);
  short ov[12];
  #pragma unroll
  for (int e = 0; e < 12; ++e) {
    int c = t * 12 + e;
    float y = (xv[e] - mean) * rs * s[c] + b[c];
    ov[e] = f2bf((1.f + sc[c]) * y + sh[c]);
  }
  #pragma unroll
  for (int j = 0; j < 3; ++j) {
    s16x4 v = { ov[j*4+0], ov[j*4+1], ov[j*4+2], ov[j*4+3] };
    *(s16x4*)(out + t * 12 + j * 4) = v;
  }
}

// ---------------------------------------------------------------------------
// GEMM 256x256x64, 8-phase (4 sub-phases/K-tile) schedule per m201 template.
// LDS layout per buffer (64 KB): A[khalf][256][32] then B[khalf][256][32],
// k-half items (16 KB) are the staging unit (2 glds/thread), T2 chunk-XOR
// swizzle within each item, counted vmcnt(8) at phases 2/4 only.
// XCD-aware bijective block swizzle, M-tile fastest within each XCD chunk.
// C[M,N] = epi(A_bf16[M,K] @ WT_bf16[N,K]^T + bias)
// EPI: 0 = store bf16; 1 = gelu->bf16; 2 = f32: resid + gate*x; 3 = f32: += gate*x
// ---------------------------------------------------------------------------
template<int EPI>
__global__ __launch_bounds__(512, 2)
void gemm256(const short* __restrict__ A, int K, int N, int split,
             const short* __restrict__ W0, const short* __restrict__ W1,
             const float* __restrict__ b0, const float* __restrict__ b1,
             void* __restrict__ out0, void* __restrict__ out1,
             const float* __restrict__ r0, const float* __restrict__ r1,
             const float* __restrict__ g0, const float* __restrict__ g1)
{
  __shared__ __align__(16) short lds[65536];   // 128 KiB: 2 bufs x 64 KB
  const int tid = threadIdx.x;
  const int lane = tid & 63, w = tid >> 6;
  const int wm = w >> 2, wn = w & 3;
  const int l15 = lane & 15, lg = lane >> 4;

  // XCD-aware bijective remap (m204), M-tile fastest
  const int gx = gridDim.x;
  const int nwg = gx * gridDim.y;
  const int lin = blockIdx.y * gx + blockIdx.x;
  const int q8 = nwg >> 3, r8 = nwg & 7;
  const int xcd = lin & 7, loc = lin >> 3;
  const int nid = (xcd < r8 ? xcd * (q8 + 1) : r8 * (q8 + 1) + (xcd - r8) * q8) + loc;
  const int bm = nid % gx, bn = nid / gx;

  const bool is1 = bm >= split;
  const int m0 = bm * 256, n0 = bn * 256;
  const short* WT = is1 ? W1 : W0;
  const float* bias = is1 ? b1 : b0;
  const int nt = K >> 6;

  f32x4 acc[8][4];
  #pragma unroll
  for (int i = 0; i < 8; ++i)
    #pragma unroll
    for (int j = 0; j < 4; ++j)
      acc[i][j] = f32x4{0.f, 0.f, 0.f, 0.f};

  // stage one k-half item (one matrix, 256 rows x 32 k = 16 KB), 2 glds/thread
  auto stage_item = [&](const short* mat, int grow0, int tt, int kh, int ldsOff) {
    const int kb = tt * 64 + kh * 32;
    #pragma unroll
    for (int l = 0; l < 2; ++l) {
      const int chrow = w * 32 + l * 16 + (lane >> 2);
      const int lc = (lane & 3) ^ ((chrow >> 1) & 3);
      GLDS16(mat + (size_t)(grow0 + chrow) * K + kb + lc * 8,
             lds + ldsOff + (w * 2 + l) * 512);
    }
  };

  const int rA0 = wm * 128 + l15;
  const int rB0 = wn * 64 + l15;
  const int cofs = (lg ^ ((l15 >> 1) & 3)) * 8;   // swizzled k-chunk offset

  s16x8 av[4], bv[4];
  auto ldA4 = [&](int c, int ks, int mfb) {
    const short* base = lds + c * 32768 + ks * 8192;
    #pragma unroll
    for (int i = 0; i < 4; ++i)
      av[i] = *(const s16x8*)(base + (rA0 + (mfb + i) * 16) * 32 + cofs);
  };
  auto ldB4 = [&](int c, int ks) {
    const short* base = lds + c * 32768 + 16384 + ks * 8192;
    #pragma unroll
    for (int i = 0; i < 4; ++i)
      bv[i] = *(const s16x8*)(base + (rB0 + i * 16) * 32 + cofs);
  };
  auto quad = [&](int mfb) {
    __builtin_amdgcn_s_setprio(1);
    #pragma unroll
    for (int i = 0; i < 4; ++i)
      #pragma unroll
      for (int j = 0; j < 4; ++j)
        acc[mfb + i][j] = __builtin_amdgcn_mfma_f32_16x16x32_bf16(
            av[i], bv[j], acc[mfb + i][j], 0, 0, 0);
    __builtin_amdgcn_s_setprio(0);
  };

  // prologue: tile0 (4 items) + k0 of tile1 (2 items)
  stage_item(A, m0, 0, 0, 0);
  stage_item(WT, n0, 0, 0, 16384);
  stage_item(A, m0, 0, 1, 8192);
  stage_item(WT, n0, 0, 1, 24576);
  if (nt > 1) {
    stage_item(A, m0, 1, 0, 32768);
    stage_item(WT, n0, 1, 0, 49152);
  }
  asm volatile("s_waitcnt vmcnt(8)" ::: "memory");
  __builtin_amdgcn_s_barrier();
  __builtin_amdgcn_sched_barrier(0);

  for (int t = 0; t < nt; ++t) {
    const int c = t & 1;
    const int cb = c * 32768, cnb = (c ^ 1) * 32768;
    // ---- phase 1: ks0, mf 0-3 (reads 8, stages A-k1(t+1))
    ldA4(c, 0, 0);
    ldB4(c, 0);
    if (t + 1 < nt) stage_item(A, m0, t + 1, 1, cnb + 8192);
    __builtin_amdgcn_s_barrier();
    __builtin_amdgcn_sched_barrier(0);
    quad(0);
    __builtin_amdgcn_s_barrier();
    __builtin_amdgcn_sched_barrier(0);
    // ---- phase 2: ks0, mf 4-7 (reads 4, stages B-k1(t+1), vmcnt)
    ldA4(c, 0, 4);
    if (t + 1 < nt) {
      stage_item(WT, n0, t + 1, 1, cnb + 24576);
      asm volatile("s_waitcnt vmcnt(8)" ::: "memory");
    } else {
      asm volatile("s_waitcnt vmcnt(0)" ::: "memory");
    }
    __builtin_amdgcn_s_barrier();
    __builtin_amdgcn_sched_barrier(0);
    quad(4);
    __builtin_amdgcn_s_barrier();
    __builtin_amdgcn_sched_barrier(0);
    // ---- phase 3: ks1, mf 0-3 (reads 8, stages A-k0(t+2))
    ldA4(c, 1, 0);
    ldB4(c, 1);
    if (t + 2 < nt) stage_item(A, m0, t + 2, 0, cb);
    __builtin_amdgcn_s_barrier();
    __builtin_amdgcn_sched_barrier(0);
    quad(0);
    __builtin_amdgcn_s_barrier();
    __builtin_amdgcn_sched_barrier(0);
    // ---- phase 4: ks1, mf 4-7 (reads 4, stages B-k0(t+2), vmcnt)
    ldA4(c, 1, 4);
    if (t + 2 < nt) {
      stage_item(WT, n0, t + 2, 0, cb + 16384);
      asm volatile("s_waitcnt vmcnt(8)" ::: "memory");
    } else if (t + 1 < nt) {
      asm volatile("s_waitcnt vmcnt(4)" ::: "memory");
    }
    __builtin_amdgcn_s_barrier();
    __builtin_amdgcn_sched_barrier(0);
    quad(4);
    __builtin_amdgcn_s_barrier();
    __builtin_amdgcn_sched_barrier(0);
  }

  // epilogue: C frag layout col=lane&15, row=(lane>>4)*4+reg
  const int lrbase = m0 - (is1 ? split * 256 : 0);
  #pragma unroll
  for (int mf = 0; mf < 8; ++mf)
    #pragma unroll
    for (int nf = 0; nf < 4; ++nf) {
      int col = n0 + wn * 64 + nf * 16 + l15;
      float bvs = bias[col];
      #pragma unroll
      for (int r = 0; r < 4; ++r) {
        int row = lrbase + wm * 128 + mf * 16 + lg * 4 + r;
        float x = acc[mf][nf][r] + bvs;
        if constexpr (EPI == 0) {
          short* o = (short*)(is1 ? out1 : out0);
          o[(size_t)row * N + col] = f2bf(x);
        } else if constexpr (EPI == 1) {
          float g = 0.5f * x * (1.f + tanhf(0.7978845608028654f * (x + 0.044715f * x * x * x)));
          short* o = (short*)(is1 ? out1 : out0);
          o[(size_t)row * N + col] = f2bf(g);
        } else if constexpr (EPI == 2) {
          const float* resid = is1 ? r1 : r0;
          const float* gate = is1 ? g1 : g0;
          float* o = (float*)(is1 ? out1 : out0);
          o[(size_t)row * N + col] = resid[(size_t)row * N + col] + gate[col] * x;
        } else {
          const float* gate = is1 ? g1 : g0;
          float* o = (float*)(is1 ? out1 : out0);
          size_t ix = (size_t)row * N + col;
          o[ix] = o[ix] + gate[col] * x;
        }
      }
    }
}

// ---------------------------------------------------------------------------
// 4) per-(token, head) RMS norm + RoPE for q,k -> [NH][LTOT][HD] bf16
// ---------------------------------------------------------------------------
__global__ __launch_bounds__(256)
void qkvr(const short* __restrict__ qkv, const float* __restrict__ pe,
          const float* __restrict__ qn_img, const float* __restrict__ kn_img,
          const float* __restrict__ qn_txt, const float* __restrict__ kn_txt,
          short* __restrict__ Qh, short* __restrict__ Kh)
{
  const int w = threadIdx.x >> 6, lane = threadIdx.x & 63;
  const int tok = blockIdx.x * 4 + w;
  const int h = blockIdx.y;
  const float* qn = (tok < LTXT) ? qn_txt : qn_img;
  const float* kn = (tok < LTXT) ? kn_txt : kn_img;
  const size_t base = (size_t)tok * 9216 + (size_t)h * HD + lane * 2;
  const float4 p4 = *(const float4*)(pe + ((size_t)tok * 64 + lane) * 4);
  {
    s16x2 qs = *(const s16x2*)(qkv + base);
    float x0 = bf2f(qs[0]), x1 = bf2f(qs[1]);
    float sq = x0 * x0 + x1 * x1;
    for (int xm = 1; xm < 64; xm <<= 1) sq += __shfl_xor(sq, xm);
    float r = rsqrtf(sq * (1.f / HD) + 1e-6f);
    x0 = x0 * r * qn[lane * 2]; x1 = x1 * r * qn[lane * 2 + 1];
    s16x2 o = { f2bf(p4.x * x0 + p4.y * x1), f2bf(p4.z * x0 + p4.w * x1) };
    *(s16x2*)(Qh + ((size_t)h * LTOT + tok) * HD + lane * 2) = o;
  }
  {
    s16x2 ks = *(const s16x2*)(qkv + base + HDIM);
    float x0 = bf2f(ks[0]), x1 = bf2f(ks[1]);
    float sq = x0 * x0 + x1 * x1;
    for (int xm = 1; xm < 64; xm <<= 1) sq += __shfl_xor(sq, xm);
    float r = rsqrtf(sq * (1.f / HD) + 1e-6f);
    x0 = x0 * r * kn[lane * 2]; x1 = x1 * r * kn[lane * 2 + 1];
    s16x2 o = { f2bf(p4.x * x0 + p4.y * x1), f2bf(p4.z * x0 + p4.w * x1) };
    *(s16x2*)(Kh + ((size_t)h * LTOT + tok) * HD + lane * 2) = o;
  }
}

// ---------------------------------------------------------------------------
// 5) V transpose: qkv v-slice -> VT[NH][HD][LTOT] bf16. grid (LTOT/64, NH).
// ---------------------------------------------------------------------------
__global__ __launch_bounds__(256)
void vt_k(const short* __restrict__ qkv, short* __restrict__ VT)
{
  __shared__ __align__(16) short Vs[64][136];
  const int h = blockIdx.y, tok0 = blockIdx.x * 64;
  const int t = threadIdx.x;
  #pragma unroll
  for (int rep = 0; rep < 4; ++rep) {
    int idx = rep * 256 + t;
    int tk = idx >> 4, oct = idx & 15;
    *(s16x8*)(&Vs[tk][oct * 8]) =
        *(const s16x8*)(qkv + (size_t)(tok0 + tk) * 9216 + 6144 + (size_t)h * HD + oct * 8);
  }
  __syncthreads();
  #pragma unroll
  for (int rep = 0; rep < 4; ++rep) {
    int idx = rep * 256 + t;
    int d = idx >> 3, tg = idx & 7;
    s16x8 o;
    #pragma unroll
    for (int j = 0; j < 8; ++j) o[j] = Vs[tg * 8 + j][d];
    *(s16x8*)(VT + ((size_t)h * HD + d) * LTOT + tok0 + tg * 8) = o;
  }
}

// ---------------------------------------------------------------------------
// 6) Flash attention. grid (LTOT/128, NH), block 256.
// ---------------------------------------------------------------------------
__global__ __launch_bounds__(256, 2)
void attn_k(const short* __restrict__ Qh, const short* __restrict__ Kh,
            const short* __restrict__ VT, short* __restrict__ out)
{
  __shared__ __align__(16) short Ps[4][32][72];
  const int t = threadIdx.x, lane = t & 63, w = t >> 6;
  const int l15 = lane & 15, lg = lane >> 4;
  const int h = blockIdx.y;
  const int qrow = blockIdx.x * 128 + w * 32;

  s16x8 qf[2][4];
  #pragma unroll
  for (int mf = 0; mf < 2; ++mf)
    #pragma unroll
    for (int ks = 0; ks < 4; ++ks)
      qf[mf][ks] = *(const s16x8*)(Qh + ((size_t)h * LTOT + qrow + mf * 16 + l15) * HD + ks * 32 + lg * 8);

  f32x4 O[2][8];
  #pragma unroll
  for (int mf = 0; mf < 2; ++mf)
    #pragma unroll
    for (int dt = 0; dt < 8; ++dt) O[mf][dt] = f32x4{0.f, 0.f, 0.f, 0.f};
  float mrow[2][4], lrow[2][4];
  #pragma unroll
  for (int mf = 0; mf < 2; ++mf)
    #pragma unroll
    for (int r = 0; r < 4; ++r) { mrow[mf][r] = -1e30f; lrow[mf][r] = 0.f; }

  for (int kt = 0; kt < LTOT / 64; ++kt) {
    const int k0 = kt * 64;
    f32x4 S[2][4];
    #pragma unroll
    for (int mf = 0; mf < 2; ++mf)
      #pragma unroll
      for (int jt = 0; jt < 4; ++jt) S[mf][jt] = f32x4{0.f, 0.f, 0.f, 0.f};
    #pragma unroll
    for (int ks = 0; ks < 4; ++ks)
      #pragma unroll
      for (int jt = 0; jt < 4; ++jt) {
        s16x8 kf = *(const s16x8*)(Kh + ((size_t)h * LTOT + k0 + jt * 16 + l15) * HD + ks * 32 + lg * 8);
        S[0][jt] = __builtin_amdgcn_mfma_f32_16x16x32_bf16(qf[0][ks], kf, S[0][jt], 0, 0, 0);
        S[1][jt] = __builtin_amdgcn_mfma_f32_16x16x32_bf16(qf[1][ks], kf, S[1][jt], 0, 0, 0);
      }
    #pragma unroll
    for (int mf = 0; mf < 2; ++mf) {
      const float scl = 0.08838834764831845f;
      #pragma unroll
      for (int jt = 0; jt < 4; ++jt) S[mf][jt] *= scl;
      float pm[4];
      #pragma unroll
      for (int r = 0; r < 4; ++r)
        pm[r] = fmaxf(fmaxf(S[mf][0][r], S[mf][1][r]), fmaxf(S[mf][2][r], S[mf][3][r]));
      for (int xm = 1; xm < 16; xm <<= 1)
        #pragma unroll
        for (int r = 0; r < 4; ++r) pm[r] = fmaxf(pm[r], __shfl_xor(pm[r], xm));
      f32x4 corrv;
      #pragma unroll
      for (int r = 0; r < 4; ++r) {
        float mn = fmaxf(mrow[mf][r], pm[r]);
        corrv[r] = __expf(mrow[mf][r] - mn);
        mrow[mf][r] = mn;
      }
      float rs[4] = {0.f, 0.f, 0.f, 0.f};
      #pragma unroll
      for (int jt = 0; jt < 4; ++jt)
        #pragma unroll
        for (int r = 0; r < 4; ++r) {
          float p = __expf(S[mf][jt][r] - mrow[mf][r]);
          S[mf][jt][r] = p;
          rs[r] += p;
        }
      for (int xm = 1; xm < 16; xm <<= 1)
        #pragma unroll
        for (int r = 0; r < 4; ++r) rs[r] += __shfl_xor(rs[r], xm);
      #pragma unroll
      for (int r = 0; r < 4; ++r) lrow[mf][r] = lrow[mf][r] * corrv[r] + rs[r];
      #pragma unroll
      for (int dt = 0; dt < 8; ++dt) O[mf][dt] *= corrv;
      #pragma unroll
      for (int jt = 0; jt < 4; ++jt)
        #pragma unroll
        for (int r = 0; r < 4; ++r)
          Ps[w][mf * 16 + lg * 4 + r][jt * 16 + l15] = f2bf(S[mf][jt][r]);
    }
    asm volatile("s_waitcnt lgkmcnt(0)" ::: "memory");
    __builtin_amdgcn_sched_barrier(0);
    #pragma unroll
    for (int kk2 = 0; kk2 < 2; ++kk2) {
      s16x8 pf0 = *(const s16x8*)(&Ps[w][l15][kk2 * 32 + lg * 8]);
      s16x8 pf1 = *(const s16x8*)(&Ps[w][16 + l15][kk2 * 32 + lg * 8]);
      #pragma unroll
      for (int dt = 0; dt < 8; ++dt) {
        s16x8 vf = *(const s16x8*)(VT + ((size_t)h * HD + dt * 16 + l15) * LTOT + k0 + kk2 * 32 + lg * 8);
        O[0][dt] = __builtin_amdgcn_mfma_f32_16x16x32_bf16(pf0, vf, O[0][dt], 0, 0, 0);
        O[1][dt] = __builtin_amdgcn_mfma_f32_16x16x32_bf16(pf1, vf, O[1][dt], 0, 0, 0);
      }
    }
    asm volatile("s_waitcnt lgkmcnt(0)" ::: "memory");
    __builtin_amdgcn_sched_barrier(0);
  }
  #pragma unroll
  for (int mf = 0; mf < 2; ++mf) {
    f32x4 inv;
    #pragma unroll
    for (int r = 0; r < 4; ++r) inv[r] = 1.f / lrow[mf][r];
    #pragma unroll
    for (int dt = 0; dt < 8; ++dt) {
      f32x4 o = O[mf][dt] * inv;
      #pragma unroll
      for (int r = 0; r < 4; ++r)
        out[(size_t)(qrow + mf * 16 + lg * 4 + r) * HDIM + (size_t)h * HD + dt * 16 + l15] = f2bf(o[r]);
    }
  }
}

// ---------------------------------------------------------------------------
extern "C" void kernel_launch(void* const* d_in, const int* in_sizes, int n_in,
                              void* d_out, int out_size, void* d_ws, size_t ws_size,
                              hipStream_t stream)
{
  (void)in_sizes; (void)n_in; (void)out_size;
  const float* img = (const float*)d_in[0];
  const float* txt = (const float*)d_in[1];
  const float* vec = (const float*)d_in[2];
  const float* pe  = (const float*)d_in[3];
  const float* Pi[16]; const float* Pt[16];
  for (int i = 0; i < 16; ++i) Pi[i] = (const float*)d_in[4 + i];
  for (int i = 0; i < 16; ++i) Pt[i] = (const float*)d_in[20 + i];
  // 0 mod_w,1 mod_b,2 ln1_s,3 ln1_b,4 qkv_w,5 qkv_b,6 qn,7 kn,8 proj_w,
  // 9 proj_b,10 ln2_s,11 ln2_b,12 mlp_w1,13 mlp_b1,14 mlp_w2,15 mlp_b2

  char* ws = (char*)d_ws;
  float* MODI = (float*)(ws + 0);
  float* MODT = (float*)(ws + 73728);
  short* XMI  = (short*)(ws + 147456);        // [2304][3072] bf16 img-first
  short* XMT  = (short*)(ws + 12730368);
  short* QKV  = (short*)(ws + 14303232);      // [2304][9216] bf16, txt-first rows
  short* QHh  = (short*)(ws + 56770560);      // [24][2304][128]
  short* KHh  = (short*)(ws + 70926336);
  short* VTt  = (short*)(ws + 85082112);      // [24][128][2304]
  short* ATT  = (short*)(ws + 99237888);      // [2304][3072] txt-first rows
  short* H1   = (short*)(ws + 14303232);      // reuse QKV+QH region: [2304][12288] img-first
  short* WTA  = (short*)(ws + 113393664);     // 75.5 MB transposed-weight buf A
  short* WTB  = (short*)(ws + 188891136);     // 75.5 MB transposed-weight buf B
  if (ws_size < (size_t)264388608) return;
  float* outI = (float*)d_out;
  float* outT = outI + (size_t)LIMG * HDIM;

  // 1) modulation vectors
  mod_gemv<<<dim3(72, 2), 256, 0, stream>>>(vec, Pi[0], Pi[1], Pt[0], Pt[1], MODI, MODT);
  // 2) LN1 + modulate
  ln_mod<<<dim3(LTOT), 256, 0, stream>>>(img, txt, LIMG, Pi[2], Pi[3], Pt[2], Pt[3],
                                         MODI, MODT, 0, 1, XMI, XMT);
  // 3) QKV: convert weights, merged gemm (XM img-first, split=8)
  wconv<<<dim3(48, 144), 256, 0, stream>>>(Pi[4], WTA, HDIM, 3 * HDIM);
  wconv<<<dim3(48, 144), 256, 0, stream>>>(Pt[4], WTB, HDIM, 3 * HDIM);
  gemm256<0><<<dim3(9, 36), 512, 0, stream>>>(XMI, HDIM, 3 * HDIM, 8,
      WTA, WTB, Pi[5], Pt[5],
      QKV + (size_t)LTXT * 9216, QKV, nullptr, nullptr, nullptr, nullptr);
  // 4) RMS + RoPE
  qkvr<<<dim3(LTOT / 4, NHEADS), 256, 0, stream>>>(QKV, pe, Pi[6], Pi[7], Pt[6], Pt[7], QHh, KHh);
  // 5) V transpose
  vt_k<<<dim3(LTOT / 64, NHEADS), 256, 0, stream>>>(QKV, VTt);
  // 6) attention
  attn_k<<<dim3(LTOT / 128, NHEADS), 256, 0, stream>>>(QHh, KHh, VTt, ATT);
  // 7) proj + gated residual -> d_out (ATT txt-first, split=1: stream0=txt)
  wconv<<<dim3(48, 48), 256, 0, stream>>>(Pt[8], WTA, HDIM, HDIM);
  wconv<<<dim3(48, 48), 256, 0, stream>>>(Pi[8], WTB, HDIM, HDIM);
  gemm256<2><<<dim3(9, 12), 512, 0, stream>>>(ATT, HDIM, HDIM, 1,
      WTA, WTB, Pt[9], Pi[9], outT, outI, txt, img,
      MODT + 2 * HDIM, MODI + 2 * HDIM);
  // 8) LN2 + modulate
  ln_mod<<<dim3(LTOT), 256, 0, stream>>>(outI, outT, LIMG, Pi[10], Pi[11], Pt[10], Pt[11],
                                         MODI, MODT, 3, 4, XMI, XMT);
  // 9) MLP1 + gelu (XM img-first, split=8) -> H1 img-first
  wconv<<<dim3(48, 192), 256, 0, stream>>>(Pi[12], WTA, HDIM, MLPD);
  wconv<<<dim3(48, 192), 256, 0, stream>>>(Pt[12], WTB, HDIM, MLPD);
  gemm256<1><<<dim3(9, 48), 512, 0, stream>>>(XMI, HDIM, MLPD, 8,
      WTA, WTB, Pi[13], Pt[13],
      H1, H1 + (size_t)LIMG * MLPD, nullptr, nullptr, nullptr, nullptr);
  // 10) MLP2 + gated residual add (H1 img-first, split=8)
  wconv<<<dim3(192, 48), 256, 0, stream>>>(Pi[14], WTA, MLPD, HDIM);
  wconv<<<dim3(192, 48), 256, 0, stream>>>(Pt[14], WTB, MLPD, HDIM);
  gemm256<3><<<dim3(9, 12), 512, 0, stream>>>(H1, MLPD, HDIM, 8,
      WTA, WTB, Pi[15], Pt[15], outI, outT, nullptr, nullptr,
      MODI + 5 * HDIM, MODT + 5 * HDIM);
}